// Round 3
// baseline (1580.950 us; speedup 1.0000x reference)
//
#include <hip/hip_runtime.h>
#include <cstdint>
#include <cstddef>

typedef unsigned short u16;
typedef unsigned int u32;
typedef __attribute__((ext_vector_type(8))) short bf16x8s;
typedef __attribute__((ext_vector_type(4))) float f32x4;

__device__ __forceinline__ u16 f2bf(float f){
  union { float f; unsigned u; } v; v.f = f;
  unsigned r = v.u + 0x7FFFu + ((v.u >> 16) & 1u);
  return (u16)(r >> 16);
}
__device__ __forceinline__ float bf2f(u16 h){
  union { unsigned u; float f; } v; v.u = ((unsigned)h) << 16;
  return v.f;
}

// ---------------- fp32 -> bf16 convert ----------------
__global__ __launch_bounds__(256) void cvt_kernel(const float* __restrict__ in,
                                                  u16* __restrict__ out, int n){
  int i = blockIdx.x*256 + threadIdx.x;
  if (i < n) out[i] = f2bf(in[i]);
}

// ---------------- temb branch: tvec[b][col] = temb@Wt^T + bt + bqkv ----------------
__global__ __launch_bounds__(256) void temb_kernel(const float* __restrict__ temb,
                                                   const float* __restrict__ Wt,
                                                   const float* __restrict__ bt,
                                                   const float* __restrict__ bqkv,
                                                   float* __restrict__ tvec){
  int idx = blockIdx.x*256 + threadIdx.x;
  if (idx >= 16*3456) return;
  int b = idx / 3456, col = idx % 3456;
  const float* tp = temb + (size_t)b*1152;
  const float* wp = Wt + (size_t)col*1152;
  float s = 0.f;
  for (int k=0;k<1152;k++) s += tp[k]*wp[k];
  tvec[idx] = s + bt[col] + bqkv[col];
}

// ---------------- row RMSNorm (no affine), fp32 in -> bf16 out ----------------
__global__ __launch_bounds__(256) void rms_kernel(const float* __restrict__ in,
                                                  u16* __restrict__ out, int C){
  int row = blockIdx.x;
  const float* p = in + (size_t)row*C;
  float ss = 0.f;
  for (int c = threadIdx.x; c < C; c += 256){ float v = p[c]; ss += v*v; }
  #pragma unroll
  for (int d=1; d<64; d<<=1) ss += __shfl_xor(ss, d);
  __shared__ float wsum[4];
  if ((threadIdx.x & 63) == 0) wsum[threadIdx.x>>6] = ss;
  __syncthreads();
  float tot = wsum[0]+wsum[1]+wsum[2]+wsum[3];
  float r = rsqrtf(tot/(float)C + 1e-6f);
  u16* o = out + (size_t)row*C;
  for (int c = threadIdx.x; c < C; c += 256) o[c] = f2bf(p[c]*r);
}

// ---------------- GEMM: Y[M][N] = A[M][K](bf16) @ B[N][K]^T(bf16), fused epilogues ----------------
// 1D grid (xcd-swizzled). MODE 0: QKV scatter; 1: PROJ; 2: GATE; 3: UP; 4: DOWN.
template<int MODE>
__global__ __launch_bounds__(256) void gemm_kernel(
    const u16* __restrict__ A, const u16* __restrict__ B,
    int M, int N, int K, int nbx,
    const float* __restrict__ bias, const float* __restrict__ fextra,
    const u16* __restrict__ gextra, void* __restrict__ outv,
    u16* __restrict__ out2, u16* __restrict__ out3)
{
  __shared__ __align__(16) u16 As[128*32];
  __shared__ __align__(16) u16 Bs[128*32];
  const int lane = threadIdx.x & 63;
  const int wv   = threadIdx.x >> 6;
  const int wr   = wv >> 1, wc = wv & 1;
  // bijective XCD swizzle (gridDim.x % 8 == 0 for all launches)
  int nwg = (int)gridDim.x;
  int id  = (int)blockIdx.x;
  id = (id & 7)*(nwg >> 3) + (id >> 3);
  const long n0 = (long)(id % nbx) * 128;
  const long m0 = (long)(id / nbx) * 128;

  f32x4 acc[4][4];
  #pragma unroll
  for (int i=0;i<4;i++)
    #pragma unroll
    for (int j=0;j<4;j++) acc[i][j] = (f32x4){0.f,0.f,0.f,0.f};

  const int srow = lane >> 2;        // 0..15 rows within a 16-row shot
  const int scol = (lane & 3) * 8;   // element offset within BK=32

  for (int kt = 0; kt < K; kt += 32) {
    #pragma unroll
    for (int c=0;c<2;c++){
      int s = wv*2 + c;              // shot 0..7, 16 rows each
      const u16* ga = A + (size_t)(m0 + s*16 + srow)*K + kt + scol;
      const u16* gb = B + (size_t)(n0 + s*16 + srow)*K + kt + scol;
      __builtin_amdgcn_global_load_lds((const __attribute__((address_space(1))) void*)ga,
          (__attribute__((address_space(3))) void*)(As + s*512), 16, 0, 0);
      __builtin_amdgcn_global_load_lds((const __attribute__((address_space(1))) void*)gb,
          (__attribute__((address_space(3))) void*)(Bs + s*512), 16, 0, 0);
    }
    __syncthreads();
    const int kb = (lane>>4)*8;
    bf16x8s af[4], bfr[4];
    #pragma unroll
    for (int i=0;i<4;i++)
      af[i] = *(const bf16x8s*)(As + (wr*64 + i*16 + (lane&15))*32 + kb);
    #pragma unroll
    for (int j=0;j<4;j++)
      bfr[j] = *(const bf16x8s*)(Bs + (wc*64 + j*16 + (lane&15))*32 + kb);
    #pragma unroll
    for (int i=0;i<4;i++)
      #pragma unroll
      for (int j=0;j<4;j++)
        acc[i][j] = __builtin_amdgcn_mfma_f32_16x16x32_bf16(af[i], bfr[j], acc[i][j], 0,0,0);
    __syncthreads();
  }

  const int lr = (lane>>4)*4, lc = lane&15;
  #pragma unroll
  for (int i=0;i<4;i++){
    #pragma unroll
    for (int j=0;j<4;j++){
      long colg = n0 + wc*64 + j*16 + lc;
      long rowg0 = m0 + wr*64 + i*16 + lr;
      if (MODE==0){
        int cg = (int)colg;
        int which = cg / 1152;
        int rem = cg - which*1152;
        int hh = rem / 72, dd = rem - hh*72;
        int b = (int)(rowg0 >> 10), n = (int)(rowg0 & 1023);
        size_t bh = (size_t)(b*16 + hh);
        float tadd = fextra[(size_t)b*3456 + colg];
        if (which == 2){
          ushort4 vv;
          vv.x = f2bf(acc[i][j][0] + tadd);
          vv.y = f2bf(acc[i][j][1] + tadd);
          vv.z = f2bf(acc[i][j][2] + tadd);
          vv.w = f2bf(acc[i][j][3] + tadd);
          *(ushort4*)(out3 + (bh*72 + dd)*1024 + n) = vv;
        } else {
          u16* dst = (which==0) ? (u16*)outv : out2;
          #pragma unroll
          for (int r=0;r<4;r++)
            dst[(bh*1024 + (size_t)(n + r))*72 + dd] = f2bf(acc[i][j][r] + tadd);
        }
      } else {
        #pragma unroll
        for (int r=0;r<4;r++){
          long rowg = rowg0 + r;
          float v = acc[i][j][r];
          size_t oi = (size_t)rowg*N + colg;
          if (MODE==1){
            v += bias[colg] + fextra[oi];
            ((float*)outv)[oi] = v;
          } else if (MODE==2){
            v += bias[colg];
            ((u16*)outv)[oi] = f2bf(v);
          } else if (MODE==3){
            float u = v + bias[colg];
            float g = bf2f(gextra[oi]);
            float h = (g / (1.f + __expf(-g))) * u;
            ((u16*)outv)[oi] = f2bf(h);
          } else {
            v += bias[colg] + fextra[oi];
            ((float*)outv)[oi] = v;
          }
        }
      }
    }
  }
}

// ---------------- per-(b,h,n): q/k RMS(+weight) + axial RoPE, IN PLACE ----------------
// Q/K: [B*H*N][72] bf16. Q additionally pre-scaled by 1/sqrt(72).
__global__ __launch_bounds__(256) void qkrope_kernel(
    u16* __restrict__ Q, u16* __restrict__ K,
    const float* __restrict__ qn_w, const float* __restrict__ kn_w,
    const float* __restrict__ cos_y, const float* __restrict__ sin_y,
    const float* __restrict__ cos_x, const float* __restrict__ sin_x)
{
  const int gw   = blockIdx.x*4 + (threadIdx.x>>6);   // row over B*H*N = 262144
  const int lane = threadIdx.x & 63;
  const int n = gw & 1023;
  const int d0 = lane*2;
  const bool act = d0 < 72;
  const float scale = 0.11785113019775793f;  // 1/sqrt(72), folded into q

  u16* qp = Q + (size_t)gw*72;
  u16* kp = K + (size_t)gw*72;
  float q0=0,q1=0,k0=0,k1=0,wq0=0,wq1=0,wk0=0,wk1=0;
  if (act){
    q0 = bf2f(qp[d0]); q1 = bf2f(qp[d0+1]);
    k0 = bf2f(kp[d0]); k1 = bf2f(kp[d0+1]);
    wq0 = qn_w[d0]; wq1 = qn_w[d0+1];
    wk0 = kn_w[d0]; wk1 = kn_w[d0+1];
  }
  float ssq = q0*q0 + q1*q1;
  float ssk = k0*k0 + k1*k1;
  #pragma unroll
  for (int d=1; d<64; d<<=1){ ssq += __shfl_xor(ssq,d); ssk += __shfl_xor(ssk,d); }
  const float rq = rsqrtf(ssq*(1.f/72.f) + 1e-6f);
  const float rk = rsqrtf(ssk*(1.f/72.f) + 1e-6f);
  float qn0 = q0*rq*wq0, qn1 = q1*rq*wq1;
  float kn0 = k0*rk*wk0, kn1 = k1*rk*wk1;

  int dh = d0 % 36;
  const bool first = (dh < 18);
  int partner = first ? lane+9 : lane-9;
  if (!act) partner = lane;
  float pq0 = __shfl(qn0, partner), pq1 = __shfl(qn1, partner);
  float pk0 = __shfl(kn0, partner), pk1 = __shfl(kn1, partner);
  if (act){
    const float* cp = (d0 < 36) ? cos_y : cos_x;
    const float* sp = (d0 < 36) ? sin_y : sin_x;
    float c0 = cp[n*36+dh], c1 = cp[n*36+dh+1];
    float s0 = sp[n*36+dh], s1 = sp[n*36+dh+1];
    float sgn = first ? -1.f : 1.f;
    float qo0 = (qn0*c0 + sgn*pq0*s0)*scale, qo1 = (qn1*c1 + sgn*pq1*s1)*scale;
    float ko0 = kn0*c0 + sgn*pk0*s0,         ko1 = kn1*c1 + sgn*pk1*s1;
    *(unsigned*)(qp + d0) = (unsigned)f2bf(qo0) | ((unsigned)f2bf(qo1)<<16);
    *(unsigned*)(kp + d0) = (unsigned)f2bf(ko0) | ((unsigned)f2bf(ko1)<<16);
  }
}

// ---------------- flash attention (no-max softmax, swapped QK^T, KVB=128) ----------------
// Q/K: [bh][1024][72] bf16 (q pre-scaled); Vt: [bh][72][1024]; O: [b][n][1152] at head offset.
__global__ __launch_bounds__(256) void attn_kernel(
    const u16* __restrict__ Q, const u16* __restrict__ K,
    const u16* __restrict__ Vt, u16* __restrict__ O)
{
  const int bh = blockIdx.x;       // 0..255
  const int q0 = blockIdx.y * 64;  // 16 q tiles
  const int lane = threadIdx.x & 63;
  const int wv   = threadIdx.x >> 6;
  const int g = lane >> 4, c = lane & 15;
  const int b = bh >> 4, h = bh & 15;

  __shared__ __align__(16) u16 Plds[4][16][128];   // per-wave P^T->P transpose, XOR-swizzled
  char* pbase = (char*)Plds + wv*4096;
  const int swz = (c & 7) << 4;
  const bf16x8s zf = {0,0,0,0,0,0,0,0};

  const u16* Qp = Q + ((size_t)bh*1024 + q0 + wv*16)*72;
  const u16* Kp = K + (size_t)bh*1024*72;
  const u16* Vp = Vt + (size_t)bh*72*1024;

  // Q as B-operand: lane holds Q[q=c][d=8g..8g+7] (+32; +64 only g==0)
  bf16x8s qf0, qf1, qf2;
  {
    const u16* qrow = Qp + (size_t)c*72 + g*8;
    qf0 = *(const bf16x8s*)(qrow);
    qf1 = *(const bf16x8s*)(qrow + 32);
    qf2 = (g==0) ? *(const bf16x8s*)(Qp + (size_t)c*72 + 64) : zf;
  }

  f32x4 oacc[5];
  #pragma unroll
  for (int c5=0;c5<5;c5++) oacc[c5] = (f32x4){0.f,0.f,0.f,0.f};
  float lsum = 0.f;

  for (int kv0 = 0; kv0 < 1024; kv0 += 128) {
    float p[8][4];
    // S^T = K·Q^T (scores pre-scaled via q); p = exp(s)
    #pragma unroll
    for (int nf=0; nf<8; nf++){
      f32x4 sc = (f32x4){0.f,0.f,0.f,0.f};
      const u16* krow = Kp + (size_t)(kv0 + nf*16 + c)*72;
      bf16x8s kf0 = *(const bf16x8s*)(krow + g*8);
      bf16x8s kf1 = *(const bf16x8s*)(krow + 32 + g*8);
      bf16x8s kf2 = (g==0) ? *(const bf16x8s*)(krow + 64) : zf;
      sc = __builtin_amdgcn_mfma_f32_16x16x32_bf16(kf0, qf0, sc,0,0,0);
      sc = __builtin_amdgcn_mfma_f32_16x16x32_bf16(kf1, qf1, sc,0,0,0);
      sc = __builtin_amdgcn_mfma_f32_16x16x32_bf16(kf2, qf2, sc,0,0,0);
      #pragma unroll
      for (int r=0;r<4;r++){
        float pv = __expf(sc[r]);
        p[nf][r] = pv;
        lsum += pv;
      }
    }
    // pack -> LDS transpose: lane holds (q=c, k=16nf+4g+r); write rows q, swizzled
    #pragma unroll
    for (int nf=0; nf<8; nf++){
      u32 w0 = (u32)f2bf(p[nf][0]) | ((u32)f2bf(p[nf][1]) << 16);
      u32 w1 = (u32)f2bf(p[nf][2]) | ((u32)f2bf(p[nf][3]) << 16);
      int kb = 32*nf + 8*g;
      *(u32*)(pbase + c*256 + ( kb      ^ swz)) = w0;
      *(u32*)(pbase + c*256 + ((kb + 4) ^ swz)) = w1;
    }
    asm volatile("" ::: "memory");
    bf16x8s pa[4];
    #pragma unroll
    for (int w=0; w<4; w++)
      pa[w] = *(const bf16x8s*)(pbase + c*256 + ((w*64 + g*16) ^ swz));

    // PV: oacc[c5] += P(16q x 128k) · V(128k x 16d)
    #pragma unroll
    for (int c5=0; c5<5; c5++){
      #pragma unroll
      for (int w=0; w<4; w++){
        bf16x8s vf = zf;
        if (c5 < 4 || c < 8)
          vf = *(const bf16x8s*)(Vp + (size_t)(c5*16 + c)*1024 + kv0 + w*32 + g*8);
        oacc[c5] = __builtin_amdgcn_mfma_f32_16x16x32_bf16(pa[w], vf, oacc[c5],0,0,0);
      }
    }
  }

  // reduce l across k-groups (lanes with same q=c), then broadcast to O-row owners
  lsum += __shfl_xor(lsum, 16);
  lsum += __shfl_xor(lsum, 32);
  float linv[4];
  #pragma unroll
  for (int r=0;r<4;r++)
    linv[r] = 1.0f / __shfl(lsum, 4*g + r);

  size_t obase = ((size_t)b*1024)*1152 + (size_t)h*72;
  #pragma unroll
  for (int c5=0;c5<5;c5++){
    int d = c5*16 + c;
    if (d < 72){
      #pragma unroll
      for (int r=0;r<4;r++){
        int n = q0 + wv*16 + 4*g + r;
        O[obase + (size_t)n*1152 + d] = f2bf(oacc[c5][r]*linv[r]);
      }
    }
  }
}

extern "C" void kernel_launch(void* const* d_in, const int* in_sizes, int n_in,
                              void* d_out, int out_size, void* d_ws, size_t ws_size,
                              hipStream_t stream) {
  const float* x    = (const float*)d_in[0];
  const float* temb = (const float*)d_in[1];
  const float* cos_y= (const float*)d_in[2];
  const float* sin_y= (const float*)d_in[3];
  const float* cos_x= (const float*)d_in[4];
  const float* sin_x= (const float*)d_in[5];
  const float* Wqkv = (const float*)d_in[6];
  const float* bqkv = (const float*)d_in[7];
  const float* Wt   = (const float*)d_in[8];
  const float* bt   = (const float*)d_in[9];
  const float* Wp   = (const float*)d_in[10];
  const float* bp   = (const float*)d_in[11];
  const float* qn_w = (const float*)d_in[12];
  const float* kn_w = (const float*)d_in[13];
  const float* Wg   = (const float*)d_in[14];
  const float* bg   = (const float*)d_in[15];
  const float* Wu   = (const float*)d_in[16];
  const float* bu   = (const float*)d_in[17];
  const float* Wd   = (const float*)d_in[18];
  const float* bd   = (const float*)d_in[19];

  char* ws = (char*)d_ws;
  size_t off = 0;
  auto alloc = [&](size_t bytes)->void*{
    off = (off + 255) & ~(size_t)255;
    void* p = ws + off; off += bytes; return p;
  };

  u16*   wbuf  = (u16*)alloc((size_t)3456*1152*2);          // shared bf16 weight buffer (max size)
  float* tvec  = (float*)alloc((size_t)16*3456*4);
  u16*   xn_bf = (u16*)alloc((size_t)16384*1152*2);         // norm1 out -> o (attn out) -> xn2
  u16*   qt    = (u16*)alloc((size_t)262144*72*2);          // gbuf starts here later
  u16*   kt    = (u16*)alloc((size_t)262144*72*2);
  u16*   vt    = (u16*)alloc((size_t)256*72*1024*2);
  if (off > ws_size) return;   // diagnostic guard: clean fail instead of OOB crash

  u16*   o_bf   = xn_bf;
  u16*   xn2_bf = xn_bf;
  u16*   gbuf   = qt;          // 100.7 MB <= qt+kt+vt region (113.2 MB)
  float* x1     = (float*)d_out;

  // norm1 + temb branch
  rms_kernel<<<16384,256,0,stream>>>(x, xn_bf, 1152);
  temb_kernel<<<(16*3456+255)/256,256,0,stream>>>(temb, Wt, bt, bqkv, tvec);

  // QKV GEMM (scatter epilogue -> qt/kt/vt)
  cvt_kernel<<<(3456*1152+255)/256,256,0,stream>>>(Wqkv, wbuf, 3456*1152);
  gemm_kernel<0><<<27*128,256,0,stream>>>(
      xn_bf, wbuf, 16384, 3456, 1152, 27, nullptr, tvec, nullptr, qt, kt, vt);

  // q/k RMS + RoPE in place (q pre-scaled by 1/sqrt(72))
  qkrope_kernel<<<65536,256,0,stream>>>(qt, kt, qn_w, kn_w, cos_y, sin_y, cos_x, sin_x);

  // attention -> o_bf
  attn_kernel<<<dim3(256,16),256,0,stream>>>(qt, kt, vt, o_bf);

  // proj + residual -> x1 (= d_out, fp32)
  cvt_kernel<<<(1152*1152+255)/256,256,0,stream>>>(Wp, wbuf, 1152*1152);
  gemm_kernel<1><<<9*128,256,0,stream>>>(
      o_bf, wbuf, 16384, 1152, 1152, 9, bp, x, nullptr, x1, nullptr, nullptr);

  // norm2
  rms_kernel<<<16384,256,0,stream>>>(x1, xn2_bf, 1152);

  // gate
  cvt_kernel<<<(3072*1152+255)/256,256,0,stream>>>(Wg, wbuf, 3072*1152);
  gemm_kernel<2><<<24*128,256,0,stream>>>(
      xn2_bf, wbuf, 16384, 3072, 1152, 24, bg, nullptr, nullptr, gbuf, nullptr, nullptr);

  // up (+ silu(g)*u fused)
  cvt_kernel<<<(3072*1152+255)/256,256,0,stream>>>(Wu, wbuf, 3072*1152);
  gemm_kernel<3><<<24*128,256,0,stream>>>(
      xn2_bf, wbuf, 16384, 3072, 1152, 24, bu, nullptr, gbuf, gbuf, nullptr, nullptr);

  // down + residual -> d_out (reads x1 == d_out element-wise, race-free)
  cvt_kernel<<<(1152*3072+255)/256,256,0,stream>>>(Wd, wbuf, 1152*3072);
  gemm_kernel<4><<<9*128,256,0,stream>>>(
      gbuf, wbuf, 16384, 1152, 3072, 9, bd, x1, nullptr, (float*)d_out, nullptr, nullptr);
}

// Round 4
// 1243.554 us; speedup vs baseline: 1.2713x; 1.2713x over previous
//
#include <hip/hip_runtime.h>
#include <cstdint>
#include <cstddef>

typedef unsigned short u16;
typedef unsigned int u32;
typedef __attribute__((ext_vector_type(8))) short bf16x8s;
typedef __attribute__((ext_vector_type(4))) float f32x4;

__device__ __forceinline__ u16 f2bf(float f){
  union { float f; unsigned u; } v; v.f = f;
  unsigned r = v.u + 0x7FFFu + ((v.u >> 16) & 1u);
  return (u16)(r >> 16);
}
__device__ __forceinline__ float bf2f(u16 h){
  union { unsigned u; float f; } v; v.u = ((unsigned)h) << 16;
  return v.f;
}

// ---------------- fp32 -> bf16 convert ----------------
__global__ __launch_bounds__(256) void cvt_kernel(const float* __restrict__ in,
                                                  u16* __restrict__ out, int n){
  int i = blockIdx.x*256 + threadIdx.x;
  if (i < n) out[i] = f2bf(in[i]);
}

// ---------------- temb branch: tvec[b][col] = temb@Wt^T + bt + bqkv ----------------
__global__ __launch_bounds__(256) void temb_kernel(const float* __restrict__ temb,
                                                   const float* __restrict__ Wt,
                                                   const float* __restrict__ bt,
                                                   const float* __restrict__ bqkv,
                                                   float* __restrict__ tvec){
  int idx = blockIdx.x*256 + threadIdx.x;
  if (idx >= 16*3456) return;
  int b = idx / 3456, col = idx % 3456;
  const float* tp = temb + (size_t)b*1152;
  const float* wp = Wt + (size_t)col*1152;
  float s = 0.f;
  for (int k=0;k<1152;k++) s += tp[k]*wp[k];
  tvec[idx] = s + bt[col] + bqkv[col];
}

// ---------------- row RMSNorm (no affine), fp32 in -> bf16 out ----------------
__global__ __launch_bounds__(256) void rms_kernel(const float* __restrict__ in,
                                                  u16* __restrict__ out, int C){
  int row = blockIdx.x;
  const float* p = in + (size_t)row*C;
  float ss = 0.f;
  for (int c = threadIdx.x; c < C; c += 256){ float v = p[c]; ss += v*v; }
  #pragma unroll
  for (int d=1; d<64; d<<=1) ss += __shfl_xor(ss, d);
  __shared__ float wsum[4];
  if ((threadIdx.x & 63) == 0) wsum[threadIdx.x>>6] = ss;
  __syncthreads();
  float tot = wsum[0]+wsum[1]+wsum[2]+wsum[3];
  float r = rsqrtf(tot/(float)C + 1e-6f);
  u16* o = out + (size_t)row*C;
  for (int c = threadIdx.x; c < C; c += 256) o[c] = f2bf(p[c]*r);
}

// ---------------- GEMM: Y[M][N] = A[M][K](bf16) @ B[N][K]^T(bf16), fused epilogues ----------------
// 1D grid (xcd-swizzled). MODE 0: QKV scatter; 1: PROJ; 2: GATE; 3: UP; 4: DOWN.
template<int MODE>
__global__ __launch_bounds__(256) void gemm_kernel(
    const u16* __restrict__ A, const u16* __restrict__ B,
    int M, int N, int K, int nbx,
    const float* __restrict__ bias, const float* __restrict__ fextra,
    const u16* __restrict__ gextra, void* __restrict__ outv,
    u16* __restrict__ out2, u16* __restrict__ out3)
{
  __shared__ __align__(16) u16 As[128*32];
  __shared__ __align__(16) u16 Bs[128*32];
  const int lane = threadIdx.x & 63;
  const int wv   = threadIdx.x >> 6;
  const int wr   = wv >> 1, wc = wv & 1;
  // bijective XCD swizzle (gridDim.x % 8 == 0 for all launches)
  int nwg = (int)gridDim.x;
  int id  = (int)blockIdx.x;
  id = (id & 7)*(nwg >> 3) + (id >> 3);
  const long n0 = (long)(id % nbx) * 128;
  const long m0 = (long)(id / nbx) * 128;

  f32x4 acc[4][4];
  #pragma unroll
  for (int i=0;i<4;i++)
    #pragma unroll
    for (int j=0;j<4;j++) acc[i][j] = (f32x4){0.f,0.f,0.f,0.f};

  const int srow = lane >> 2;        // 0..15 rows within a 16-row shot
  const int scol = (lane & 3) * 8;   // element offset within BK=32

  for (int kt = 0; kt < K; kt += 32) {
    #pragma unroll
    for (int c=0;c<2;c++){
      int s = wv*2 + c;              // shot 0..7, 16 rows each
      const u16* ga = A + (size_t)(m0 + s*16 + srow)*K + kt + scol;
      const u16* gb = B + (size_t)(n0 + s*16 + srow)*K + kt + scol;
      __builtin_amdgcn_global_load_lds((const __attribute__((address_space(1))) void*)ga,
          (__attribute__((address_space(3))) void*)(As + s*512), 16, 0, 0);
      __builtin_amdgcn_global_load_lds((const __attribute__((address_space(1))) void*)gb,
          (__attribute__((address_space(3))) void*)(Bs + s*512), 16, 0, 0);
    }
    __syncthreads();
    const int kb = (lane>>4)*8;
    bf16x8s af[4], bfr[4];
    #pragma unroll
    for (int i=0;i<4;i++)
      af[i] = *(const bf16x8s*)(As + (wr*64 + i*16 + (lane&15))*32 + kb);
    #pragma unroll
    for (int j=0;j<4;j++)
      bfr[j] = *(const bf16x8s*)(Bs + (wc*64 + j*16 + (lane&15))*32 + kb);
    #pragma unroll
    for (int i=0;i<4;i++)
      #pragma unroll
      for (int j=0;j<4;j++)
        acc[i][j] = __builtin_amdgcn_mfma_f32_16x16x32_bf16(af[i], bfr[j], acc[i][j], 0,0,0);
    __syncthreads();
  }

  const int lr = (lane>>4)*4, lc = lane&15;
  #pragma unroll
  for (int i=0;i<4;i++){
    #pragma unroll
    for (int j=0;j<4;j++){
      long colg = n0 + wc*64 + j*16 + lc;
      long rowg0 = m0 + wr*64 + i*16 + lr;
      if (MODE==0){
        int cg = (int)colg;
        int which = cg / 1152;
        int rem = cg - which*1152;
        int hh = rem / 72, dd = rem - hh*72;
        int b = (int)(rowg0 >> 10), n = (int)(rowg0 & 1023);
        size_t bh = (size_t)(b*16 + hh);
        float tadd = fextra[(size_t)b*3456 + colg];
        if (which == 2){
          ushort4 vv;
          vv.x = f2bf(acc[i][j][0] + tadd);
          vv.y = f2bf(acc[i][j][1] + tadd);
          vv.z = f2bf(acc[i][j][2] + tadd);
          vv.w = f2bf(acc[i][j][3] + tadd);
          *(ushort4*)(out3 + (bh*72 + dd)*1024 + n) = vv;
        } else {
          u16* dst = (which==0) ? (u16*)outv : out2;
          #pragma unroll
          for (int r=0;r<4;r++)
            dst[(bh*1024 + (size_t)(n + r))*72 + dd] = f2bf(acc[i][j][r] + tadd);
        }
      } else {
        #pragma unroll
        for (int r=0;r<4;r++){
          long rowg = rowg0 + r;
          float v = acc[i][j][r];
          size_t oi = (size_t)rowg*N + colg;
          if (MODE==1){
            v += bias[colg] + fextra[oi];
            ((float*)outv)[oi] = v;
          } else if (MODE==2){
            v += bias[colg];
            ((u16*)outv)[oi] = f2bf(v);
          } else if (MODE==3){
            float u = v + bias[colg];
            float g = bf2f(gextra[oi]);
            float h = (g / (1.f + __expf(-g))) * u;
            ((u16*)outv)[oi] = f2bf(h);
          } else {
            v += bias[colg] + fextra[oi];
            ((float*)outv)[oi] = v;
          }
        }
      }
    }
  }
}

// ---------------- per-(b,h,n): q/k RMS(+weight) + axial RoPE, IN PLACE ----------------
// Q/K: [B*H*N][72] bf16. Q additionally pre-scaled by 1/sqrt(72).
__global__ __launch_bounds__(256) void qkrope_kernel(
    u16* __restrict__ Q, u16* __restrict__ K,
    const float* __restrict__ qn_w, const float* __restrict__ kn_w,
    const float* __restrict__ cos_y, const float* __restrict__ sin_y,
    const float* __restrict__ cos_x, const float* __restrict__ sin_x)
{
  const int gw   = blockIdx.x*4 + (threadIdx.x>>6);   // row over B*H*N = 262144
  const int lane = threadIdx.x & 63;
  const int n = gw & 1023;
  const int d0 = lane*2;
  const bool act = d0 < 72;
  const float scale = 0.11785113019775793f;  // 1/sqrt(72), folded into q

  u16* qp = Q + (size_t)gw*72;
  u16* kp = K + (size_t)gw*72;
  float q0=0,q1=0,k0=0,k1=0,wq0=0,wq1=0,wk0=0,wk1=0;
  if (act){
    q0 = bf2f(qp[d0]); q1 = bf2f(qp[d0+1]);
    k0 = bf2f(kp[d0]); k1 = bf2f(kp[d0+1]);
    wq0 = qn_w[d0]; wq1 = qn_w[d0+1];
    wk0 = kn_w[d0]; wk1 = kn_w[d0+1];
  }
  float ssq = q0*q0 + q1*q1;
  float ssk = k0*k0 + k1*k1;
  #pragma unroll
  for (int d=1; d<64; d<<=1){ ssq += __shfl_xor(ssq,d); ssk += __shfl_xor(ssk,d); }
  const float rq = rsqrtf(ssq*(1.f/72.f) + 1e-6f);
  const float rk = rsqrtf(ssk*(1.f/72.f) + 1e-6f);
  float qn0 = q0*rq*wq0, qn1 = q1*rq*wq1;
  float kn0 = k0*rk*wk0, kn1 = k1*rk*wk1;

  int dh = d0 % 36;
  const bool first = (dh < 18);
  int partner = first ? lane+9 : lane-9;
  if (!act) partner = lane;
  float pq0 = __shfl(qn0, partner), pq1 = __shfl(qn1, partner);
  float pk0 = __shfl(kn0, partner), pk1 = __shfl(kn1, partner);
  if (act){
    const float* cp = (d0 < 36) ? cos_y : cos_x;
    const float* sp = (d0 < 36) ? sin_y : sin_x;
    float c0 = cp[n*36+dh], c1 = cp[n*36+dh+1];
    float s0 = sp[n*36+dh], s1 = sp[n*36+dh+1];
    float sgn = first ? -1.f : 1.f;
    float qo0 = (qn0*c0 + sgn*pq0*s0)*scale, qo1 = (qn1*c1 + sgn*pq1*s1)*scale;
    float ko0 = kn0*c0 + sgn*pk0*s0,         ko1 = kn1*c1 + sgn*pk1*s1;
    *(unsigned*)(qp + d0) = (unsigned)f2bf(qo0) | ((unsigned)f2bf(qo1)<<16);
    *(unsigned*)(kp + d0) = (unsigned)f2bf(ko0) | ((unsigned)f2bf(ko1)<<16);
  }
}

// ---------------- flash attention v3: 4 waves x 32 q-rows (QBLK=128), KVB=64 ----------------
// Q/K: [bh][1024][72] bf16 (q pre-scaled by 1/sqrt(72)); Vt: [bh][72][1024];
// O: [b][n][1152] at head offset. No-max softmax (|s|<=8.5 guaranteed by RMS-normed q,k).
// Grid 2048: decode keeps the 8 q-blocks of one head on one XCD (b%8 affinity).
__global__ __launch_bounds__(256, 3) void attn_kernel(
    const u16* __restrict__ Q, const u16* __restrict__ K,
    const u16* __restrict__ Vt, u16* __restrict__ O)
{
  const int tid  = threadIdx.x;
  const int lane = tid & 63;
  const int wv   = tid >> 6;            // 0..3
  const int g = lane >> 4, c = lane & 15;
  const int bid  = blockIdx.x;
  const int head = (bid >> 6) * 8 + (bid & 7);   // XCD affinity: b%8 == head%8
  const int q0   = ((bid >> 3) & 7) * 128;
  const int b = head >> 4, h = head & 15;

  __shared__ __align__(16) u16 Vlds[80][72];      // [d][k] for current kv-tile; rows 72..79 zero
  __shared__ __align__(16) u16 Plds[8][16][64];   // [wv*2+s][q][k], XOR-swizzled rows

  const bf16x8s zf = {0,0,0,0,0,0,0,0};
  const u16* Kp = K + (size_t)head*1024*72;
  const u16* Qb = Q + ((size_t)head*1024 + q0 + wv*32)*72;
  const char* Vg = (const char*)(Vt + (size_t)head*72*1024);

  // Q fragments for 2 q-sets (32 rows/wave), B-operand layout
  bf16x8s qf[2][3];
  #pragma unroll
  for (int s=0;s<2;s++){
    const u16* qrow = Qb + (size_t)(s*16 + c)*72;
    qf[s][0] = *(const bf16x8s*)(qrow + g*8);
    qf[s][1] = *(const bf16x8s*)(qrow + 32 + g*8);
    qf[s][2] = (g==0) ? *(const bf16x8s*)(qrow + 64) : zf;
  }

  f32x4 oacc[2][5];
  float lsum[2] = {0.f, 0.f};
  #pragma unroll
  for (int s=0;s<2;s++)
    #pragma unroll
    for (int c5=0;c5<5;c5++) oacc[s][c5] = (f32x4){0.f,0.f,0.f,0.f};

  char* pb0 = (char*)Plds + (wv*2+0)*2048 + c*128;
  char* pb1 = pb0 + 2048;
  const int swz = (c & 7) << 4;

  // V tile staging: 576 x 16B chunks (72 d-rows x 128B); thread t: chunks t, 256+t, (t<64: 512+t)
  int4 vr0, vr1, vr2;
  {
    vr0 = *(const int4*)(Vg + ((tid    )>>3)*2048 + ((tid    )&7)*16);
    vr1 = *(const int4*)(Vg + ((256+tid)>>3)*2048 + ((256+tid)&7)*16);
    if (tid < 64) vr2 = *(const int4*)(Vg + ((512+tid)>>3)*2048 + ((512+tid)&7)*16);
  }
  if (tid < 288) ((u32*)&Vlds[72][0])[tid] = 0u;   // zero pad rows 72..79 (disjoint from staging region)
  {
    *(int4*)((char*)Vlds + ((tid    )>>3)*144 + ((tid    )&7)*16) = vr0;
    *(int4*)((char*)Vlds + ((256+tid)>>3)*144 + ((256+tid)&7)*16) = vr1;
    if (tid < 64) *(int4*)((char*)Vlds + ((512+tid)>>3)*144 + ((512+tid)&7)*16) = vr2;
  }

  for (int t = 0; t < 16; ++t){
    const int kv0 = t*64;
    __syncthreads();                       // tile t staged (and pads zeroed)
    if (t < 15){                           // prefetch tile t+1 into regs
      const char* vs = Vg + (kv0+64)*2;
      vr0 = *(const int4*)(vs + ((tid    )>>3)*2048 + ((tid    )&7)*16);
      vr1 = *(const int4*)(vs + ((256+tid)>>3)*2048 + ((256+tid)&7)*16);
      if (tid < 64) vr2 = *(const int4*)(vs + ((512+tid)>>3)*2048 + ((512+tid)&7)*16);
    }

    // QK^T (swapped: S^T lane (g,c) -> k-row = nf*16+4g+r, q = c), exp, pack -> Plds
    #pragma unroll
    for (int nf=0; nf<4; nf++){
      const u16* krow = Kp + (size_t)(kv0 + nf*16 + c)*72;
      bf16x8s kf0 = *(const bf16x8s*)(krow + g*8);
      bf16x8s kf1 = *(const bf16x8s*)(krow + 32 + g*8);
      bf16x8s kf2 = (g==0) ? *(const bf16x8s*)(krow + 64) : zf;
      #pragma unroll
      for (int s=0;s<2;s++){
        f32x4 sc = (f32x4){0.f,0.f,0.f,0.f};
        sc = __builtin_amdgcn_mfma_f32_16x16x32_bf16(kf0, qf[s][0], sc,0,0,0);
        sc = __builtin_amdgcn_mfma_f32_16x16x32_bf16(kf1, qf[s][1], sc,0,0,0);
        sc = __builtin_amdgcn_mfma_f32_16x16x32_bf16(kf2, qf[s][2], sc,0,0,0);
        float p0 = __expf(sc[0]), p1 = __expf(sc[1]);
        float p2 = __expf(sc[2]), p3 = __expf(sc[3]);
        lsum[s] += (p0+p1) + (p2+p3);
        u32 w0 = (u32)f2bf(p0) | ((u32)f2bf(p1) << 16);
        u32 w1 = (u32)f2bf(p2) | ((u32)f2bf(p3) << 16);
        char* pb = s ? pb1 : pb0;
        int kb = nf*32 + g*8;
        *(u32*)(pb + ( kb      ^ swz)) = w0;
        *(u32*)(pb + ((kb + 4) ^ swz)) = w1;
      }
    }
    asm volatile("" ::: "memory");
    bf16x8s pa[2][2];
    #pragma unroll
    for (int s=0;s<2;s++)
      #pragma unroll
      for (int w2=0;w2<2;w2++)
        pa[s][w2] = *(const bf16x8s*)((s?pb1:pb0) + ((w2*64 + g*16) ^ swz));

    // PV: V frag read once, used by both q-sets
    #pragma unroll
    for (int c5=0;c5<5;c5++){
      #pragma unroll
      for (int w2=0;w2<2;w2++){
        bf16x8s vf = *(const bf16x8s*)((const char*)Vlds + (size_t)(c5*16+c)*144 + w2*64 + g*16);
        oacc[0][c5] = __builtin_amdgcn_mfma_f32_16x16x32_bf16(pa[0][w2], vf, oacc[0][c5],0,0,0);
        oacc[1][c5] = __builtin_amdgcn_mfma_f32_16x16x32_bf16(pa[1][w2], vf, oacc[1][c5],0,0,0);
      }
    }

    if (t < 15){
      __syncthreads();                     // all waves done reading Vlds tile t
      *(int4*)((char*)Vlds + ((tid    )>>3)*144 + ((tid    )&7)*16) = vr0;
      *(int4*)((char*)Vlds + ((256+tid)>>3)*144 + ((256+tid)&7)*16) = vr1;
      if (tid < 64) *(int4*)((char*)Vlds + ((512+tid)>>3)*144 + ((512+tid)&7)*16) = vr2;
    }
  }

  // l reduction: sum over the 4 g-groups (same q=c), then fetch per-output-row
  size_t obase = (size_t)b*1024*1152 + (size_t)h*72;
  #pragma unroll
  for (int s=0;s<2;s++){
    float ls = lsum[s];
    ls += __shfl_xor(ls, 16);
    ls += __shfl_xor(ls, 32);
    float linv[4];
    #pragma unroll
    for (int r=0;r<4;r++) linv[r] = 1.0f / __shfl(ls, 4*g + r);
    #pragma unroll
    for (int c5=0;c5<5;c5++){
      int d = c5*16 + c;
      if (d < 72){
        #pragma unroll
        for (int r=0;r<4;r++){
          int n = q0 + wv*32 + s*16 + 4*g + r;
          O[obase + (size_t)n*1152 + d] = f2bf(oacc[s][c5][r]*linv[r]);
        }
      }
    }
  }
}

extern "C" void kernel_launch(void* const* d_in, const int* in_sizes, int n_in,
                              void* d_out, int out_size, void* d_ws, size_t ws_size,
                              hipStream_t stream) {
  const float* x    = (const float*)d_in[0];
  const float* temb = (const float*)d_in[1];
  const float* cos_y= (const float*)d_in[2];
  const float* sin_y= (const float*)d_in[3];
  const float* cos_x= (const float*)d_in[4];
  const float* sin_x= (const float*)d_in[5];
  const float* Wqkv = (const float*)d_in[6];
  const float* bqkv = (const float*)d_in[7];
  const float* Wt   = (const float*)d_in[8];
  const float* bt   = (const float*)d_in[9];
  const float* Wp   = (const float*)d_in[10];
  const float* bp   = (const float*)d_in[11];
  const float* qn_w = (const float*)d_in[12];
  const float* kn_w = (const float*)d_in[13];
  const float* Wg   = (const float*)d_in[14];
  const float* bg   = (const float*)d_in[15];
  const float* Wu   = (const float*)d_in[16];
  const float* bu   = (const float*)d_in[17];
  const float* Wd   = (const float*)d_in[18];
  const float* bd   = (const float*)d_in[19];

  char* ws = (char*)d_ws;
  size_t off = 0;
  auto alloc = [&](size_t bytes)->void*{
    off = (off + 255) & ~(size_t)255;
    void* p = ws + off; off += bytes; return p;
  };

  u16*   wbuf  = (u16*)alloc((size_t)3456*1152*2);          // shared bf16 weight buffer (max size)
  float* tvec  = (float*)alloc((size_t)16*3456*4);
  u16*   xn_bf = (u16*)alloc((size_t)16384*1152*2);         // norm1 out -> o (attn out) -> xn2
  u16*   qt    = (u16*)alloc((size_t)262144*72*2);          // gbuf starts here later
  u16*   kt    = (u16*)alloc((size_t)262144*72*2);
  u16*   vt    = (u16*)alloc((size_t)256*72*1024*2);
  if (off > ws_size) return;   // diagnostic guard: clean fail instead of OOB crash

  u16*   o_bf   = xn_bf;
  u16*   xn2_bf = xn_bf;
  u16*   gbuf   = qt;          // 100.7 MB <= qt+kt+vt region (113.2 MB)
  float* x1     = (float*)d_out;

  // norm1 + temb branch
  rms_kernel<<<16384,256,0,stream>>>(x, xn_bf, 1152);
  temb_kernel<<<(16*3456+255)/256,256,0,stream>>>(temb, Wt, bt, bqkv, tvec);

  // QKV GEMM (scatter epilogue -> qt/kt/vt)
  cvt_kernel<<<(3456*1152+255)/256,256,0,stream>>>(Wqkv, wbuf, 3456*1152);
  gemm_kernel<0><<<27*128,256,0,stream>>>(
      xn_bf, wbuf, 16384, 3456, 1152, 27, nullptr, tvec, nullptr, qt, kt, vt);

  // q/k RMS + RoPE in place (q pre-scaled by 1/sqrt(72))
  qkrope_kernel<<<65536,256,0,stream>>>(qt, kt, qn_w, kn_w, cos_y, sin_y, cos_x, sin_x);

  // attention -> o_bf (2048 blocks, head-XCD affinity decode inside)
  attn_kernel<<<2048,256,0,stream>>>(qt, kt, vt, o_bf);

  // proj + residual -> x1 (= d_out, fp32)
  cvt_kernel<<<(1152*1152+255)/256,256,0,stream>>>(Wp, wbuf, 1152*1152);
  gemm_kernel<1><<<9*128,256,0,stream>>>(
      o_bf, wbuf, 16384, 1152, 1152, 9, bp, x, nullptr, x1, nullptr, nullptr);

  // norm2
  rms_kernel<<<16384,256,0,stream>>>(x1, xn2_bf, 1152);

  // gate
  cvt_kernel<<<(3072*1152+255)/256,256,0,stream>>>(Wg, wbuf, 3072*1152);
  gemm_kernel<2><<<24*128,256,0,stream>>>(
      xn2_bf, wbuf, 16384, 3072, 1152, 24, bg, nullptr, nullptr, gbuf, nullptr, nullptr);

  // up (+ silu(g)*u fused)
  cvt_kernel<<<(3072*1152+255)/256,256,0,stream>>>(Wu, wbuf, 3072*1152);
  gemm_kernel<3><<<24*128,256,0,stream>>>(
      xn2_bf, wbuf, 16384, 3072, 1152, 24, bu, nullptr, gbuf, gbuf, nullptr, nullptr);

  // down + residual -> d_out (reads x1 == d_out element-wise, race-free)
  cvt_kernel<<<(1152*3072+255)/256,256,0,stream>>>(Wd, wbuf, 1152*3072);
  gemm_kernel<4><<<9*128,256,0,stream>>>(
      gbuf, wbuf, 16384, 1152, 3072, 9, bd, x1, nullptr, (float*)d_out, nullptr, nullptr);
}

// Round 5
// 1061.177 us; speedup vs baseline: 1.4898x; 1.1719x over previous
//
#include <hip/hip_runtime.h>
#include <cstdint>
#include <cstddef>

typedef unsigned short u16;
typedef unsigned int u32;
typedef __attribute__((ext_vector_type(8))) short bf16x8s;
typedef __attribute__((ext_vector_type(4))) float f32x4;

__device__ __forceinline__ u16 f2bf(float f){
  union { float f; unsigned u; } v; v.f = f;
  unsigned r = v.u + 0x7FFFu + ((v.u >> 16) & 1u);
  return (u16)(r >> 16);
}
__device__ __forceinline__ float bf2f(u16 h){
  union { unsigned u; float f; } v; v.u = ((unsigned)h) << 16;
  return v.f;
}

// ---------------- fp32 -> bf16 convert ----------------
__global__ __launch_bounds__(256) void cvt_kernel(const float* __restrict__ in,
                                                  u16* __restrict__ out, int n){
  int i = blockIdx.x*256 + threadIdx.x;
  if (i < n) out[i] = f2bf(in[i]);
}

// ---------------- Wg/Wu -> bf16 interleaved in 16-row blocks: out rows [6144][1152] ----------------
__global__ __launch_bounds__(256) void cvt_gu_kernel(const float* __restrict__ Wg,
                                                     const float* __restrict__ Wu,
                                                     u16* __restrict__ out){
  size_t i = (size_t)blockIdx.x*256 + threadIdx.x;   // over 6144*1152
  if (i >= (size_t)6144*1152) return;
  int j = (int)(i / 1152), k = (int)(i % 1152);
  int b16 = j >> 4, w = j & 15;
  int src = (b16 >> 1)*16 + w;
  const float* W = (b16 & 1) ? Wu : Wg;
  out[i] = f2bf(W[(size_t)src*1152 + k]);
}

// ---------------- temb branch: tvec[b][col] = temb@Wt^T + bt + bqkv ----------------
__global__ __launch_bounds__(256) void temb_kernel(const float* __restrict__ temb,
                                                   const float* __restrict__ Wt,
                                                   const float* __restrict__ bt,
                                                   const float* __restrict__ bqkv,
                                                   float* __restrict__ tvec){
  int idx = blockIdx.x*256 + threadIdx.x;
  if (idx >= 16*3456) return;
  int b = idx / 3456, col = idx % 3456;
  const float* tp = temb + (size_t)b*1152;
  const float* wp = Wt + (size_t)col*1152;
  float s = 0.f;
  for (int k=0;k<1152;k++) s += tp[k]*wp[k];
  tvec[idx] = s + bt[col] + bqkv[col];
}

// ---------------- row RMSNorm (no affine), fp32 in -> bf16 out ----------------
__global__ __launch_bounds__(256) void rms_kernel(const float* __restrict__ in,
                                                  u16* __restrict__ out, int C){
  int row = blockIdx.x;
  const float* p = in + (size_t)row*C;
  float ss = 0.f;
  for (int c = threadIdx.x; c < C; c += 256){ float v = p[c]; ss += v*v; }
  #pragma unroll
  for (int d=1; d<64; d<<=1) ss += __shfl_xor(ss, d);
  __shared__ float wsum[4];
  if ((threadIdx.x & 63) == 0) wsum[threadIdx.x>>6] = ss;
  __syncthreads();
  float tot = wsum[0]+wsum[1]+wsum[2]+wsum[3];
  float r = rsqrtf(tot/(float)C + 1e-6f);
  u16* o = out + (size_t)row*C;
  for (int c = threadIdx.x; c < C; c += 256) o[c] = f2bf(p[c]*r);
}

// ---------------- GEMM: Y[M][N] = A[M][K](bf16) @ B[N][K]^T(bf16), pipelined dbuf ----------------
// 1D grid (xcd-swizzled). MODE 0: QKV scatter; 1: PROJ; 4: DOWN; 5: GATE+UP fused (N=6144 interleaved).
// NT = K/32 must be EVEN (K=1152 -> 36, K=3072 -> 96).
template<int MODE>
__global__ __launch_bounds__(256, 3) void gemm_kernel(
    const u16* __restrict__ A, const u16* __restrict__ B,
    int M, int N, int K, int nbx,
    const float* __restrict__ bias, const float* __restrict__ fextra,
    void* __restrict__ outv, u16* __restrict__ out2, u16* __restrict__ out3)
{
  __shared__ __align__(16) u16 As0[128*32];
  __shared__ __align__(16) u16 Bs0[128*32];
  __shared__ __align__(16) u16 As1[128*32];
  __shared__ __align__(16) u16 Bs1[128*32];
  const int tid  = threadIdx.x;
  const int lane = tid & 63;
  const int wv   = tid >> 6;
  const int wr   = wv >> 1, wc = wv & 1;
  // bijective XCD swizzle (gridDim.x % 8 == 0 for all launches)
  int nwg = (int)gridDim.x;
  int id  = (int)blockIdx.x;
  id = (id & 7)*(nwg >> 3) + (id >> 3);
  const long n0 = (long)(id % nbx) * 128;
  const long m0 = (long)(id / nbx) * 128;

  const u16* Ab = A + (size_t)m0*K;
  const u16* Bb = B + (size_t)n0*K;
  const int srow = tid >> 2;          // 0..63
  const int spos = (tid & 3) * 8;     // element offset of 16B chunk within 32-col row

  f32x4 acc[4][4];
  #pragma unroll
  for (int i=0;i<4;i++)
    #pragma unroll
    for (int j=0;j<4;j++) acc[i][j] = (f32x4){0.f,0.f,0.f,0.f};

  // stage one 128x32 A-tile + B-tile at k-offset kt into (as,bs): 4 global_load_lds/thread
  auto stage = [&](u16* as, u16* bs, int kt){
    __builtin_amdgcn_global_load_lds(
      (const __attribute__((address_space(1))) void*)(Ab + (size_t)srow*K + kt + spos),
      (__attribute__((address_space(3))) void*)(as + wv*512), 16, 0, 0);
    __builtin_amdgcn_global_load_lds(
      (const __attribute__((address_space(1))) void*)(Ab + (size_t)(64+srow)*K + kt + spos),
      (__attribute__((address_space(3))) void*)(as + 2048 + wv*512), 16, 0, 0);
    __builtin_amdgcn_global_load_lds(
      (const __attribute__((address_space(1))) void*)(Bb + (size_t)srow*K + kt + spos),
      (__attribute__((address_space(3))) void*)(bs + wv*512), 16, 0, 0);
    __builtin_amdgcn_global_load_lds(
      (const __attribute__((address_space(1))) void*)(Bb + (size_t)(64+srow)*K + kt + spos),
      (__attribute__((address_space(3))) void*)(bs + 2048 + wv*512), 16, 0, 0);
  };
  auto compute = [&](const u16* as, const u16* bs){
    const int kb = (lane>>4)*8;
    const int lc = lane & 15;
    bf16x8s af[4], bfr[4];
    #pragma unroll
    for (int i=0;i<4;i++)
      af[i] = *(const bf16x8s*)(as + (wr*64 + i*16 + lc)*32 + kb);
    #pragma unroll
    for (int j=0;j<4;j++)
      bfr[j] = *(const bf16x8s*)(bs + (wc*64 + j*16 + lc)*32 + kb);
    #pragma unroll
    for (int i=0;i<4;i++)
      #pragma unroll
      for (int j=0;j<4;j++)
        acc[i][j] = __builtin_amdgcn_mfma_f32_16x16x32_bf16(af[i], bfr[j], acc[i][j], 0,0,0);
  };

  const int NT = K >> 5;
  // prologue: stage tile 0, drain, barrier
  stage(As0, Bs0, 0);
  asm volatile("s_waitcnt vmcnt(0)" ::: "memory");
  __builtin_amdgcn_s_barrier();
  __builtin_amdgcn_sched_barrier(0);

  for (int tp = 0; tp < NT; tp += 2){
    if (tp+1 < NT) stage(As1, Bs1, (tp+1)*32);
    compute(As0, Bs0);
    asm volatile("s_waitcnt vmcnt(0)" ::: "memory");
    __builtin_amdgcn_s_barrier();
    __builtin_amdgcn_sched_barrier(0);
    if (tp+2 < NT) stage(As0, Bs0, (tp+2)*32);
    compute(As1, Bs1);
    asm volatile("s_waitcnt vmcnt(0)" ::: "memory");
    __builtin_amdgcn_s_barrier();
    __builtin_amdgcn_sched_barrier(0);
  }

  const int lr = (lane>>4)*4, lc = lane&15;
  if (MODE==5){
    // frag pairs (0,1),(2,3): g in even frag, u in odd frag; h -> outv [M][3072]
    #pragma unroll
    for (int i=0;i<4;i++){
      #pragma unroll
      for (int jp=0;jp<2;jp++){
        long hcol = (n0>>1) + wc*32 + jp*16 + lc;
        float bgv = bias[hcol], buv = fextra[hcol];
        #pragma unroll
        for (int r=0;r<4;r++){
          long rowg = m0 + wr*64 + i*16 + lr + r;
          float gv = acc[i][2*jp][r] + bgv;
          float uv = acc[i][2*jp+1][r] + buv;
          float hv = (gv/(1.f + __expf(-gv))) * uv;
          ((u16*)outv)[(size_t)rowg*3072 + hcol] = f2bf(hv);
        }
      }
    }
    return;
  }
  #pragma unroll
  for (int i=0;i<4;i++){
    #pragma unroll
    for (int j=0;j<4;j++){
      long colg = n0 + wc*64 + j*16 + lc;
      long rowg0 = m0 + wr*64 + i*16 + lr;
      if (MODE==0){
        int cg = (int)colg;
        int which = cg / 1152;
        int rem = cg - which*1152;
        int hh = rem / 72, dd = rem - hh*72;
        int b = (int)(rowg0 >> 10), n = (int)(rowg0 & 1023);
        size_t bh = (size_t)(b*16 + hh);
        float tadd = fextra[(size_t)b*3456 + colg];
        if (which == 2){
          ushort4 vv;
          vv.x = f2bf(acc[i][j][0] + tadd);
          vv.y = f2bf(acc[i][j][1] + tadd);
          vv.z = f2bf(acc[i][j][2] + tadd);
          vv.w = f2bf(acc[i][j][3] + tadd);
          *(ushort4*)(out3 + (bh*72 + dd)*1024 + n) = vv;
        } else {
          u16* dst = (which==0) ? (u16*)outv : out2;
          #pragma unroll
          for (int r=0;r<4;r++)
            dst[(bh*1024 + (size_t)(n + r))*72 + dd] = f2bf(acc[i][j][r] + tadd);
        }
      } else {
        #pragma unroll
        for (int r=0;r<4;r++){
          long rowg = rowg0 + r;
          float v = acc[i][j][r];
          size_t oi = (size_t)rowg*N + colg;
          if (MODE==1){
            v += bias[colg] + fextra[oi];
            ((float*)outv)[oi] = v;
          } else {
            v += bias[colg] + fextra[oi];
            ((float*)outv)[oi] = v;
          }
        }
      }
    }
  }
}

// ---------------- per-(b,h,n): q/k RMS(+weight) + axial RoPE, IN PLACE ----------------
__global__ __launch_bounds__(256) void qkrope_kernel(
    u16* __restrict__ Q, u16* __restrict__ K,
    const float* __restrict__ qn_w, const float* __restrict__ kn_w,
    const float* __restrict__ cos_y, const float* __restrict__ sin_y,
    const float* __restrict__ cos_x, const float* __restrict__ sin_x)
{
  const int gw   = blockIdx.x*4 + (threadIdx.x>>6);   // row over B*H*N = 262144
  const int lane = threadIdx.x & 63;
  const int n = gw & 1023;
  const int d0 = lane*2;
  const bool act = d0 < 72;
  const float scale = 0.11785113019775793f;  // 1/sqrt(72), folded into q

  u16* qp = Q + (size_t)gw*72;
  u16* kp = K + (size_t)gw*72;
  float q0=0,q1=0,k0=0,k1=0,wq0=0,wq1=0,wk0=0,wk1=0;
  if (act){
    q0 = bf2f(qp[d0]); q1 = bf2f(qp[d0+1]);
    k0 = bf2f(kp[d0]); k1 = bf2f(kp[d0+1]);
    wq0 = qn_w[d0]; wq1 = qn_w[d0+1];
    wk0 = kn_w[d0]; wk1 = kn_w[d0+1];
  }
  float ssq = q0*q0 + q1*q1;
  float ssk = k0*k0 + k1*k1;
  #pragma unroll
  for (int d=1; d<64; d<<=1){ ssq += __shfl_xor(ssq,d); ssk += __shfl_xor(ssk,d); }
  const float rq = rsqrtf(ssq*(1.f/72.f) + 1e-6f);
  const float rk = rsqrtf(ssk*(1.f/72.f) + 1e-6f);
  float qn0 = q0*rq*wq0, qn1 = q1*rq*wq1;
  float kn0 = k0*rk*wk0, kn1 = k1*rk*wk1;

  int dh = d0 % 36;
  const bool first = (dh < 18);
  int partner = first ? lane+9 : lane-9;
  if (!act) partner = lane;
  float pq0 = __shfl(qn0, partner), pq1 = __shfl(qn1, partner);
  float pk0 = __shfl(kn0, partner), pk1 = __shfl(kn1, partner);
  if (act){
    const float* cp = (d0 < 36) ? cos_y : cos_x;
    const float* sp = (d0 < 36) ? sin_y : sin_x;
    float c0 = cp[n*36+dh], c1 = cp[n*36+dh+1];
    float s0 = sp[n*36+dh], s1 = sp[n*36+dh+1];
    float sgn = first ? -1.f : 1.f;
    float qo0 = (qn0*c0 + sgn*pq0*s0)*scale, qo1 = (qn1*c1 + sgn*pq1*s1)*scale;
    float ko0 = kn0*c0 + sgn*pk0*s0,         ko1 = kn1*c1 + sgn*pk1*s1;
    *(unsigned*)(qp + d0) = (unsigned)f2bf(qo0) | ((unsigned)f2bf(qo1)<<16);
    *(unsigned*)(kp + d0) = (unsigned)f2bf(ko0) | ((unsigned)f2bf(ko1)<<16);
  }
}

// ---------------- flash attention: 4 waves x 32 q-rows (QBLK=128), KVB=64 ----------------
__global__ __launch_bounds__(256, 3) void attn_kernel(
    const u16* __restrict__ Q, const u16* __restrict__ K,
    const u16* __restrict__ Vt, u16* __restrict__ O)
{
  const int tid  = threadIdx.x;
  const int lane = tid & 63;
  const int wv   = tid >> 6;            // 0..3
  const int g = lane >> 4, c = lane & 15;
  const int bid  = blockIdx.x;
  const int head = (bid >> 6) * 8 + (bid & 7);   // XCD affinity: b%8 == head%8
  const int q0   = ((bid >> 3) & 7) * 128;
  const int b = head >> 4, h = head & 15;

  __shared__ __align__(16) u16 Vlds[80][72];      // [d][k] for current kv-tile; rows 72..79 zero
  __shared__ __align__(16) u16 Plds[8][16][64];   // [wv*2+s][q][k], XOR-swizzled rows

  const bf16x8s zf = {0,0,0,0,0,0,0,0};
  const u16* Kp = K + (size_t)head*1024*72;
  const u16* Qb = Q + ((size_t)head*1024 + q0 + wv*32)*72;
  const char* Vg = (const char*)(Vt + (size_t)head*72*1024);

  bf16x8s qf[2][3];
  #pragma unroll
  for (int s=0;s<2;s++){
    const u16* qrow = Qb + (size_t)(s*16 + c)*72;
    qf[s][0] = *(const bf16x8s*)(qrow + g*8);
    qf[s][1] = *(const bf16x8s*)(qrow + 32 + g*8);
    qf[s][2] = (g==0) ? *(const bf16x8s*)(qrow + 64) : zf;
  }

  f32x4 oacc[2][5];
  float lsum[2] = {0.f, 0.f};
  #pragma unroll
  for (int s=0;s<2;s++)
    #pragma unroll
    for (int c5=0;c5<5;c5++) oacc[s][c5] = (f32x4){0.f,0.f,0.f,0.f};

  char* pb0 = (char*)Plds + (wv*2+0)*2048 + c*128;
  char* pb1 = pb0 + 2048;
  const int swz = (c & 7) << 4;

  int4 vr0, vr1, vr2;
  {
    vr0 = *(const int4*)(Vg + ((tid    )>>3)*2048 + ((tid    )&7)*16);
    vr1 = *(const int4*)(Vg + ((256+tid)>>3)*2048 + ((256+tid)&7)*16);
    if (tid < 64) vr2 = *(const int4*)(Vg + ((512+tid)>>3)*2048 + ((512+tid)&7)*16);
  }
  if (tid < 288) ((u32*)&Vlds[72][0])[tid] = 0u;
  {
    *(int4*)((char*)Vlds + ((tid    )>>3)*144 + ((tid    )&7)*16) = vr0;
    *(int4*)((char*)Vlds + ((256+tid)>>3)*144 + ((256+tid)&7)*16) = vr1;
    if (tid < 64) *(int4*)((char*)Vlds + ((512+tid)>>3)*144 + ((512+tid)&7)*16) = vr2;
  }

  for (int t = 0; t < 16; ++t){
    const int kv0 = t*64;
    __syncthreads();
    if (t < 15){
      const char* vs = Vg + (kv0+64)*2;
      vr0 = *(const int4*)(vs + ((tid    )>>3)*2048 + ((tid    )&7)*16);
      vr1 = *(const int4*)(vs + ((256+tid)>>3)*2048 + ((256+tid)&7)*16);
      if (tid < 64) vr2 = *(const int4*)(vs + ((512+tid)>>3)*2048 + ((512+tid)&7)*16);
    }

    #pragma unroll
    for (int nf=0; nf<4; nf++){
      const u16* krow = Kp + (size_t)(kv0 + nf*16 + c)*72;
      bf16x8s kf0 = *(const bf16x8s*)(krow + g*8);
      bf16x8s kf1 = *(const bf16x8s*)(krow + 32 + g*8);
      bf16x8s kf2 = (g==0) ? *(const bf16x8s*)(krow + 64) : zf;
      #pragma unroll
      for (int s=0;s<2;s++){
        f32x4 sc = (f32x4){0.f,0.f,0.f,0.f};
        sc = __builtin_amdgcn_mfma_f32_16x16x32_bf16(kf0, qf[s][0], sc,0,0,0);
        sc = __builtin_amdgcn_mfma_f32_16x16x32_bf16(kf1, qf[s][1], sc,0,0,0);
        sc = __builtin_amdgcn_mfma_f32_16x16x32_bf16(kf2, qf[s][2], sc,0,0,0);
        float p0 = __expf(sc[0]), p1 = __expf(sc[1]);
        float p2 = __expf(sc[2]), p3 = __expf(sc[3]);
        lsum[s] += (p0+p1) + (p2+p3);
        u32 w0 = (u32)f2bf(p0) | ((u32)f2bf(p1) << 16);
        u32 w1 = (u32)f2bf(p2) | ((u32)f2bf(p3) << 16);
        char* pb = s ? pb1 : pb0;
        int kb = nf*32 + g*8;
        *(u32*)(pb + ( kb      ^ swz)) = w0;
        *(u32*)(pb + ((kb + 4) ^ swz)) = w1;
      }
    }
    asm volatile("" ::: "memory");
    bf16x8s pa[2][2];
    #pragma unroll
    for (int s=0;s<2;s++)
      #pragma unroll
      for (int w2=0;w2<2;w2++)
        pa[s][w2] = *(const bf16x8s*)((s?pb1:pb0) + ((w2*64 + g*16) ^ swz));

    #pragma unroll
    for (int c5=0;c5<5;c5++){
      #pragma unroll
      for (int w2=0;w2<2;w2++){
        bf16x8s vf = *(const bf16x8s*)((const char*)Vlds + (size_t)(c5*16+c)*144 + w2*64 + g*16);
        oacc[0][c5] = __builtin_amdgcn_mfma_f32_16x16x32_bf16(pa[0][w2], vf, oacc[0][c5],0,0,0);
        oacc[1][c5] = __builtin_amdgcn_mfma_f32_16x16x32_bf16(pa[1][w2], vf, oacc[1][c5],0,0,0);
      }
    }

    if (t < 15){
      __syncthreads();
      *(int4*)((char*)Vlds + ((tid    )>>3)*144 + ((tid    )&7)*16) = vr0;
      *(int4*)((char*)Vlds + ((256+tid)>>3)*144 + ((256+tid)&7)*16) = vr1;
      if (tid < 64) *(int4*)((char*)Vlds + ((512+tid)>>3)*144 + ((512+tid)&7)*16) = vr2;
    }
  }

  size_t obase = (size_t)b*1024*1152 + (size_t)h*72;
  #pragma unroll
  for (int s=0;s<2;s++){
    float ls = lsum[s];
    ls += __shfl_xor(ls, 16);
    ls += __shfl_xor(ls, 32);
    float linv[4];
    #pragma unroll
    for (int r=0;r<4;r++) linv[r] = 1.0f / __shfl(ls, 4*g + r);
    #pragma unroll
    for (int c5=0;c5<5;c5++){
      int d = c5*16 + c;
      if (d < 72){
        #pragma unroll
        for (int r=0;r<4;r++){
          int n = q0 + wv*32 + s*16 + 4*g + r;
          O[obase + (size_t)n*1152 + d] = f2bf(oacc[s][c5][r]*linv[r]);
        }
      }
    }
  }
}

extern "C" void kernel_launch(void* const* d_in, const int* in_sizes, int n_in,
                              void* d_out, int out_size, void* d_ws, size_t ws_size,
                              hipStream_t stream) {
  const float* x    = (const float*)d_in[0];
  const float* temb = (const float*)d_in[1];
  const float* cos_y= (const float*)d_in[2];
  const float* sin_y= (const float*)d_in[3];
  const float* cos_x= (const float*)d_in[4];
  const float* sin_x= (const float*)d_in[5];
  const float* Wqkv = (const float*)d_in[6];
  const float* bqkv = (const float*)d_in[7];
  const float* Wt   = (const float*)d_in[8];
  const float* bt   = (const float*)d_in[9];
  const float* Wp   = (const float*)d_in[10];
  const float* bp   = (const float*)d_in[11];
  const float* qn_w = (const float*)d_in[12];
  const float* kn_w = (const float*)d_in[13];
  const float* Wg   = (const float*)d_in[14];
  const float* bg   = (const float*)d_in[15];
  const float* Wu   = (const float*)d_in[16];
  const float* bu   = (const float*)d_in[17];
  const float* Wd   = (const float*)d_in[18];
  const float* bd   = (const float*)d_in[19];

  char* ws = (char*)d_ws;
  size_t off = 0;
  auto alloc = [&](size_t bytes)->void*{
    off = (off + 255) & ~(size_t)255;
    void* p = ws + off; off += bytes; return p;
  };

  u16*   wbuf  = (u16*)alloc((size_t)6144*1152*2);          // shared bf16 weight buffer (max: gate+up interleaved)
  float* tvec  = (float*)alloc((size_t)16*3456*4);
  u16*   xn_bf = (u16*)alloc((size_t)16384*1152*2);         // norm1 out -> o (attn out) -> xn2
  u16*   qt    = (u16*)alloc((size_t)262144*72*2);          // gbuf starts here later
  u16*   kt    = (u16*)alloc((size_t)262144*72*2);
  u16*   vt    = (u16*)alloc((size_t)256*72*1024*2);
  if (off > ws_size) return;   // diagnostic guard: clean fail instead of OOB crash

  u16*   o_bf   = xn_bf;
  u16*   xn2_bf = xn_bf;
  u16*   gbuf   = qt;          // 100.7 MB <= qt+kt+vt region (113.2 MB)
  float* x1     = (float*)d_out;

  // norm1 + temb branch
  rms_kernel<<<16384,256,0,stream>>>(x, xn_bf, 1152);
  temb_kernel<<<(16*3456+255)/256,256,0,stream>>>(temb, Wt, bt, bqkv, tvec);

  // QKV GEMM (scatter epilogue -> qt/kt/vt)
  cvt_kernel<<<(3456*1152+255)/256,256,0,stream>>>(Wqkv, wbuf, 3456*1152);
  gemm_kernel<0><<<27*128,256,0,stream>>>(
      xn_bf, wbuf, 16384, 3456, 1152, 27, nullptr, tvec, qt, kt, vt);

  // q/k RMS + RoPE in place (q pre-scaled by 1/sqrt(72))
  qkrope_kernel<<<65536,256,0,stream>>>(qt, kt, qn_w, kn_w, cos_y, sin_y, cos_x, sin_x);

  // attention -> o_bf
  attn_kernel<<<2048,256,0,stream>>>(qt, kt, vt, o_bf);

  // proj + residual -> x1 (= d_out, fp32)
  cvt_kernel<<<(1152*1152+255)/256,256,0,stream>>>(Wp, wbuf, 1152*1152);
  gemm_kernel<1><<<9*128,256,0,stream>>>(
      o_bf, wbuf, 16384, 1152, 1152, 9, bp, x, x1, nullptr, nullptr);

  // norm2
  rms_kernel<<<16384,256,0,stream>>>(x1, xn2_bf, 1152);

  // gate+up fused (interleaved weights), silu in epilogue -> gbuf
  cvt_gu_kernel<<<(6144*1152+255)/256,256,0,stream>>>(Wg, Wu, wbuf);
  gemm_kernel<5><<<48*128,256,0,stream>>>(
      xn2_bf, wbuf, 16384, 6144, 1152, 48, bg, bu, gbuf, nullptr, nullptr);

  // down + residual -> d_out (reads x1 == d_out element-wise, race-free)
  cvt_kernel<<<(1152*3072+255)/256,256,0,stream>>>(Wd, wbuf, 1152*3072);
  gemm_kernel<4><<<9*128,256,0,stream>>>(
      gbuf, wbuf, 16384, 1152, 3072, 9, bd, x1, (float*)d_out, nullptr, nullptr);
}

// Round 6
// 1020.562 us; speedup vs baseline: 1.5491x; 1.0398x over previous
//
#include <hip/hip_runtime.h>
#include <cstdint>
#include <cstddef>

typedef unsigned short u16;
typedef unsigned int u32;
typedef __attribute__((ext_vector_type(8))) short bf16x8s;
typedef __attribute__((ext_vector_type(4))) float f32x4;

__device__ __forceinline__ u16 f2bf(float f){
  union { float f; unsigned u; } v; v.f = f;
  unsigned r = v.u + 0x7FFFu + ((v.u >> 16) & 1u);
  return (u16)(r >> 16);
}
__device__ __forceinline__ float bf2f(u16 h){
  union { unsigned u; float f; } v; v.u = ((unsigned)h) << 16;
  return v.f;
}

// ---------------- fp32 -> bf16 convert ----------------
__global__ __launch_bounds__(256) void cvt_kernel(const float* __restrict__ in,
                                                  u16* __restrict__ out, int n){
  int i = blockIdx.x*256 + threadIdx.x;
  if (i < n) out[i] = f2bf(in[i]);
}

// ---------------- Wg/Wu -> bf16 interleaved in 16-row blocks: out rows [6144][1152] ----------------
__global__ __launch_bounds__(256) void cvt_gu_kernel(const float* __restrict__ Wg,
                                                     const float* __restrict__ Wu,
                                                     u16* __restrict__ out){
  size_t i = (size_t)blockIdx.x*256 + threadIdx.x;   // over 6144*1152
  if (i >= (size_t)6144*1152) return;
  int j = (int)(i / 1152), k = (int)(i % 1152);
  int b16 = j >> 4, w = j & 15;
  int src = (b16 >> 1)*16 + w;
  const float* W = (b16 & 1) ? Wu : Wg;
  out[i] = f2bf(W[(size_t)src*1152 + k]);
}

// ---------------- temb branch: tvec[b][col] = temb@Wt^T + bt + bqkv ----------------
__global__ __launch_bounds__(256) void temb_kernel(const float* __restrict__ temb,
                                                   const float* __restrict__ Wt,
                                                   const float* __restrict__ bt,
                                                   const float* __restrict__ bqkv,
                                                   float* __restrict__ tvec){
  int idx = blockIdx.x*256 + threadIdx.x;
  if (idx >= 16*3456) return;
  int b = idx / 3456, col = idx % 3456;
  const float* tp = temb + (size_t)b*1152;
  const float* wp = Wt + (size_t)col*1152;
  float s = 0.f;
  for (int k=0;k<1152;k++) s += tp[k]*wp[k];
  tvec[idx] = s + bt[col] + bqkv[col];
}

// ---------------- row RMSNorm (no affine), fp32 in -> bf16 out ----------------
__global__ __launch_bounds__(256) void rms_kernel(const float* __restrict__ in,
                                                  u16* __restrict__ out, int C){
  int row = blockIdx.x;
  const float* p = in + (size_t)row*C;
  float ss = 0.f;
  for (int c = threadIdx.x; c < C; c += 256){ float v = p[c]; ss += v*v; }
  #pragma unroll
  for (int d=1; d<64; d<<=1) ss += __shfl_xor(ss, d);
  __shared__ float wsum[4];
  if ((threadIdx.x & 63) == 0) wsum[threadIdx.x>>6] = ss;
  __syncthreads();
  float tot = wsum[0]+wsum[1]+wsum[2]+wsum[3];
  float r = rsqrtf(tot/(float)C + 1e-6f);
  u16* o = out + (size_t)row*C;
  for (int c = threadIdx.x; c < C; c += 256) o[c] = f2bf(p[c]*r);
}

// ---------------- GEMM: Y[M][N] = A[M][K](bf16) @ B[N][K]^T(bf16), pipelined dbuf ----------------
// Cache-aware block order: XCD x owns m-rows [x*mdep, (x+1)*mdep); within the chunk,
// iterate n-segments of SEGW panels (B-seg <= ~2.4 MB, L2-resident), sweeping all mdep
// m-rows per segment. L3 dedupes B/A across XCDs.
// MODE 0: QKV scatter; 1: PROJ; 4: DOWN; 5: GATE+UP fused (N=6144 interleaved).
// NT = K/32 must be EVEN. Requires: nwg%8==0, (nwg/8)%nbx==0, nbx%segw==0.
template<int MODE>
__global__ __launch_bounds__(256, 3) void gemm_kernel(
    const u16* __restrict__ A, const u16* __restrict__ B,
    int M, int N, int K, int nbx, int segw,
    const float* __restrict__ bias, const float* __restrict__ fextra,
    void* __restrict__ outv, u16* __restrict__ out2, u16* __restrict__ out3)
{
  __shared__ __align__(16) u16 As0[128*32];
  __shared__ __align__(16) u16 Bs0[128*32];
  __shared__ __align__(16) u16 As1[128*32];
  __shared__ __align__(16) u16 Bs1[128*32];
  const int tid  = threadIdx.x;
  const int lane = tid & 63;
  const int wv   = tid >> 6;
  const int wr   = wv >> 1, wc = wv & 1;

  // block-id remap: xcd chunk -> n-segment -> m-sweep -> n within segment
  const int nwg  = (int)gridDim.x;
  const int bid  = (int)blockIdx.x;
  const int xcd  = bid & 7;
  const int slot = bid >> 3;              // [0, nwg/8)
  const int mdep = (nwg >> 3) / nbx;      // m-rows per xcd chunk
  const int segsz = mdep * segw;
  const int seg  = slot / segsz;
  const int rem  = slot - seg*segsz;
  const int mi   = rem / segw;
  const int ni   = seg*segw + (rem - mi*segw);
  const long m0 = (long)(xcd*mdep + mi) * 128;
  const long n0 = (long)ni * 128;

  const u16* Ab = A + (size_t)m0*K;
  const u16* Bb = B + (size_t)n0*K;
  const int srow = tid >> 2;          // 0..63
  const int spos = (tid & 3) * 8;     // element offset of 16B chunk within 32-col row

  f32x4 acc[4][4];
  #pragma unroll
  for (int i=0;i<4;i++)
    #pragma unroll
    for (int j=0;j<4;j++) acc[i][j] = (f32x4){0.f,0.f,0.f,0.f};

  auto stage = [&](u16* as, u16* bs, int kt){
    __builtin_amdgcn_global_load_lds(
      (const __attribute__((address_space(1))) void*)(Ab + (size_t)srow*K + kt + spos),
      (__attribute__((address_space(3))) void*)(as + wv*512), 16, 0, 0);
    __builtin_amdgcn_global_load_lds(
      (const __attribute__((address_space(1))) void*)(Ab + (size_t)(64+srow)*K + kt + spos),
      (__attribute__((address_space(3))) void*)(as + 2048 + wv*512), 16, 0, 0);
    __builtin_amdgcn_global_load_lds(
      (const __attribute__((address_space(1))) void*)(Bb + (size_t)srow*K + kt + spos),
      (__attribute__((address_space(3))) void*)(bs + wv*512), 16, 0, 0);
    __builtin_amdgcn_global_load_lds(
      (const __attribute__((address_space(1))) void*)(Bb + (size_t)(64+srow)*K + kt + spos),
      (__attribute__((address_space(3))) void*)(bs + 2048 + wv*512), 16, 0, 0);
  };
  auto compute = [&](const u16* as, const u16* bs){
    const int kb = (lane>>4)*8;
    const int lc = lane & 15;
    bf16x8s af[4], bfr[4];
    #pragma unroll
    for (int i=0;i<4;i++)
      af[i] = *(const bf16x8s*)(as + (wr*64 + i*16 + lc)*32 + kb);
    #pragma unroll
    for (int j=0;j<4;j++)
      bfr[j] = *(const bf16x8s*)(bs + (wc*64 + j*16 + lc)*32 + kb);
    #pragma unroll
    for (int i=0;i<4;i++)
      #pragma unroll
      for (int j=0;j<4;j++)
        acc[i][j] = __builtin_amdgcn_mfma_f32_16x16x32_bf16(af[i], bfr[j], acc[i][j], 0,0,0);
  };

  const int NT = K >> 5;
  stage(As0, Bs0, 0);
  asm volatile("s_waitcnt vmcnt(0)" ::: "memory");
  __builtin_amdgcn_s_barrier();
  __builtin_amdgcn_sched_barrier(0);

  for (int tp = 0; tp < NT; tp += 2){
    if (tp+1 < NT) stage(As1, Bs1, (tp+1)*32);
    compute(As0, Bs0);
    asm volatile("s_waitcnt vmcnt(0)" ::: "memory");
    __builtin_amdgcn_s_barrier();
    __builtin_amdgcn_sched_barrier(0);
    if (tp+2 < NT) stage(As0, Bs0, (tp+2)*32);
    compute(As1, Bs1);
    asm volatile("s_waitcnt vmcnt(0)" ::: "memory");
    __builtin_amdgcn_s_barrier();
    __builtin_amdgcn_sched_barrier(0);
  }

  const int lr = (lane>>4)*4, lc = lane&15;
  if (MODE==5){
    #pragma unroll
    for (int i=0;i<4;i++){
      #pragma unroll
      for (int jp=0;jp<2;jp++){
        long hcol = (n0>>1) + wc*32 + jp*16 + lc;
        float bgv = bias[hcol], buv = fextra[hcol];
        #pragma unroll
        for (int r=0;r<4;r++){
          long rowg = m0 + wr*64 + i*16 + lr + r;
          float gv = acc[i][2*jp][r] + bgv;
          float uv = acc[i][2*jp+1][r] + buv;
          float hv = (gv/(1.f + __expf(-gv))) * uv;
          ((u16*)outv)[(size_t)rowg*3072 + hcol] = f2bf(hv);
        }
      }
    }
    return;
  }
  #pragma unroll
  for (int i=0;i<4;i++){
    #pragma unroll
    for (int j=0;j<4;j++){
      long colg = n0 + wc*64 + j*16 + lc;
      long rowg0 = m0 + wr*64 + i*16 + lr;
      if (MODE==0){
        int cg = (int)colg;
        int which = cg / 1152;
        int rem2 = cg - which*1152;
        int hh = rem2 / 72, dd = rem2 - hh*72;
        int b = (int)(rowg0 >> 10), n = (int)(rowg0 & 1023);
        size_t bh = (size_t)(b*16 + hh);
        float tadd = fextra[(size_t)b*3456 + colg];
        if (which == 2){
          ushort4 vv;
          vv.x = f2bf(acc[i][j][0] + tadd);
          vv.y = f2bf(acc[i][j][1] + tadd);
          vv.z = f2bf(acc[i][j][2] + tadd);
          vv.w = f2bf(acc[i][j][3] + tadd);
          *(ushort4*)(out3 + (bh*72 + dd)*1024 + n) = vv;
        } else {
          u16* dst = (which==0) ? (u16*)outv : out2;
          #pragma unroll
          for (int r=0;r<4;r++)
            dst[(bh*1024 + (size_t)(n + r))*72 + dd] = f2bf(acc[i][j][r] + tadd);
        }
      } else {
        #pragma unroll
        for (int r=0;r<4;r++){
          long rowg = rowg0 + r;
          float v = acc[i][j][r];
          size_t oi = (size_t)rowg*N + colg;
          v += bias[colg] + fextra[oi];
          ((float*)outv)[oi] = v;
        }
      }
    }
  }
}

// ---------------- per-(b,h,n): q/k RMS(+weight) + axial RoPE, IN PLACE ----------------
__global__ __launch_bounds__(256) void qkrope_kernel(
    u16* __restrict__ Q, u16* __restrict__ K,
    const float* __restrict__ qn_w, const float* __restrict__ kn_w,
    const float* __restrict__ cos_y, const float* __restrict__ sin_y,
    const float* __restrict__ cos_x, const float* __restrict__ sin_x)
{
  const int gw   = blockIdx.x*4 + (threadIdx.x>>6);   // row over B*H*N = 262144
  const int lane = threadIdx.x & 63;
  const int n = gw & 1023;
  const int d0 = lane*2;
  const bool act = d0 < 72;
  const float scale = 0.11785113019775793f;  // 1/sqrt(72), folded into q

  u16* qp = Q + (size_t)gw*72;
  u16* kp = K + (size_t)gw*72;
  float q0=0,q1=0,k0=0,k1=0,wq0=0,wq1=0,wk0=0,wk1=0;
  if (act){
    q0 = bf2f(qp[d0]); q1 = bf2f(qp[d0+1]);
    k0 = bf2f(kp[d0]); k1 = bf2f(kp[d0+1]);
    wq0 = qn_w[d0]; wq1 = qn_w[d0+1];
    wk0 = kn_w[d0]; wk1 = kn_w[d0+1];
  }
  float ssq = q0*q0 + q1*q1;
  float ssk = k0*k0 + k1*k1;
  #pragma unroll
  for (int d=1; d<64; d<<=1){ ssq += __shfl_xor(ssq,d); ssk += __shfl_xor(ssk,d); }
  const float rq = rsqrtf(ssq*(1.f/72.f) + 1e-6f);
  const float rk = rsqrtf(ssk*(1.f/72.f) + 1e-6f);
  float qn0 = q0*rq*wq0, qn1 = q1*rq*wq1;
  float kn0 = k0*rk*wk0, kn1 = k1*rk*wk1;

  int dh = d0 % 36;
  const bool first = (dh < 18);
  int partner = first ? lane+9 : lane-9;
  if (!act) partner = lane;
  float pq0 = __shfl(qn0, partner), pq1 = __shfl(qn1, partner);
  float pk0 = __shfl(kn0, partner), pk1 = __shfl(kn1, partner);
  if (act){
    const float* cp = (d0 < 36) ? cos_y : cos_x;
    const float* sp = (d0 < 36) ? sin_y : sin_x;
    float c0 = cp[n*36+dh], c1 = cp[n*36+dh+1];
    float s0 = sp[n*36+dh], s1 = sp[n*36+dh+1];
    float sgn = first ? -1.f : 1.f;
    float qo0 = (qn0*c0 + sgn*pq0*s0)*scale, qo1 = (qn1*c1 + sgn*pq1*s1)*scale;
    float ko0 = kn0*c0 + sgn*pk0*s0,         ko1 = kn1*c1 + sgn*pk1*s1;
    *(unsigned*)(qp + d0) = (unsigned)f2bf(qo0) | ((unsigned)f2bf(qo1)<<16);
    *(unsigned*)(kp + d0) = (unsigned)f2bf(ko0) | ((unsigned)f2bf(ko1)<<16);
  }
}

// ---------------- flash attention: 4 waves x 32 q-rows (QBLK=128), KVB=64 ----------------
__global__ __launch_bounds__(256, 3) void attn_kernel(
    const u16* __restrict__ Q, const u16* __restrict__ K,
    const u16* __restrict__ Vt, u16* __restrict__ O)
{
  const int tid  = threadIdx.x;
  const int lane = tid & 63;
  const int wv   = tid >> 6;            // 0..3
  const int g = lane >> 4, c = lane & 15;
  const int bid  = blockIdx.x;
  const int head = (bid >> 6) * 8 + (bid & 7);   // XCD affinity: b%8 == head%8
  const int q0   = ((bid >> 3) & 7) * 128;
  const int b = head >> 4, h = head & 15;

  __shared__ __align__(16) u16 Vlds[80][72];      // [d][k] for current kv-tile; rows 72..79 zero
  __shared__ __align__(16) u16 Plds[8][16][64];   // [wv*2+s][q][k], XOR-swizzled rows

  const bf16x8s zf = {0,0,0,0,0,0,0,0};
  const u16* Kp = K + (size_t)head*1024*72;
  const u16* Qb = Q + ((size_t)head*1024 + q0 + wv*32)*72;
  const char* Vg = (const char*)(Vt + (size_t)head*72*1024);

  bf16x8s qf[2][3];
  #pragma unroll
  for (int s=0;s<2;s++){
    const u16* qrow = Qb + (size_t)(s*16 + c)*72;
    qf[s][0] = *(const bf16x8s*)(qrow + g*8);
    qf[s][1] = *(const bf16x8s*)(qrow + 32 + g*8);
    qf[s][2] = (g==0) ? *(const bf16x8s*)(qrow + 64) : zf;
  }

  f32x4 oacc[2][5];
  float lsum[2] = {0.f, 0.f};
  #pragma unroll
  for (int s=0;s<2;s++)
    #pragma unroll
    for (int c5=0;c5<5;c5++) oacc[s][c5] = (f32x4){0.f,0.f,0.f,0.f};

  char* pb0 = (char*)Plds + (wv*2+0)*2048 + c*128;
  char* pb1 = pb0 + 2048;
  const int swz = (c & 7) << 4;

  int4 vr0, vr1, vr2;
  {
    vr0 = *(const int4*)(Vg + ((tid    )>>3)*2048 + ((tid    )&7)*16);
    vr1 = *(const int4*)(Vg + ((256+tid)>>3)*2048 + ((256+tid)&7)*16);
    if (tid < 64) vr2 = *(const int4*)(Vg + ((512+tid)>>3)*2048 + ((512+tid)&7)*16);
  }
  if (tid < 288) ((u32*)&Vlds[72][0])[tid] = 0u;
  {
    *(int4*)((char*)Vlds + ((tid    )>>3)*144 + ((tid    )&7)*16) = vr0;
    *(int4*)((char*)Vlds + ((256+tid)>>3)*144 + ((256+tid)&7)*16) = vr1;
    if (tid < 64) *(int4*)((char*)Vlds + ((512+tid)>>3)*144 + ((512+tid)&7)*16) = vr2;
  }

  for (int t = 0; t < 16; ++t){
    const int kv0 = t*64;
    __syncthreads();
    if (t < 15){
      const char* vs = Vg + (kv0+64)*2;
      vr0 = *(const int4*)(vs + ((tid    )>>3)*2048 + ((tid    )&7)*16);
      vr1 = *(const int4*)(vs + ((256+tid)>>3)*2048 + ((256+tid)&7)*16);
      if (tid < 64) vr2 = *(const int4*)(vs + ((512+tid)>>3)*2048 + ((512+tid)&7)*16);
    }

    #pragma unroll
    for (int nf=0; nf<4; nf++){
      const u16* krow = Kp + (size_t)(kv0 + nf*16 + c)*72;
      bf16x8s kf0 = *(const bf16x8s*)(krow + g*8);
      bf16x8s kf1 = *(const bf16x8s*)(krow + 32 + g*8);
      bf16x8s kf2 = (g==0) ? *(const bf16x8s*)(krow + 64) : zf;
      #pragma unroll
      for (int s=0;s<2;s++){
        f32x4 sc = (f32x4){0.f,0.f,0.f,0.f};
        sc = __builtin_amdgcn_mfma_f32_16x16x32_bf16(kf0, qf[s][0], sc,0,0,0);
        sc = __builtin_amdgcn_mfma_f32_16x16x32_bf16(kf1, qf[s][1], sc,0,0,0);
        sc = __builtin_amdgcn_mfma_f32_16x16x32_bf16(kf2, qf[s][2], sc,0,0,0);
        float p0 = __expf(sc[0]), p1 = __expf(sc[1]);
        float p2 = __expf(sc[2]), p3 = __expf(sc[3]);
        lsum[s] += (p0+p1) + (p2+p3);
        u32 w0 = (u32)f2bf(p0) | ((u32)f2bf(p1) << 16);
        u32 w1 = (u32)f2bf(p2) | ((u32)f2bf(p3) << 16);
        char* pb = s ? pb1 : pb0;
        int kb = nf*32 + g*8;
        *(u32*)(pb + ( kb      ^ swz)) = w0;
        *(u32*)(pb + ((kb + 4) ^ swz)) = w1;
      }
    }
    asm volatile("" ::: "memory");
    bf16x8s pa[2][2];
    #pragma unroll
    for (int s=0;s<2;s++)
      #pragma unroll
      for (int w2=0;w2<2;w2++)
        pa[s][w2] = *(const bf16x8s*)((s?pb1:pb0) + ((w2*64 + g*16) ^ swz));

    #pragma unroll
    for (int c5=0;c5<5;c5++){
      #pragma unroll
      for (int w2=0;w2<2;w2++){
        bf16x8s vf = *(const bf16x8s*)((const char*)Vlds + (size_t)(c5*16+c)*144 + w2*64 + g*16);
        oacc[0][c5] = __builtin_amdgcn_mfma_f32_16x16x32_bf16(pa[0][w2], vf, oacc[0][c5],0,0,0);
        oacc[1][c5] = __builtin_amdgcn_mfma_f32_16x16x32_bf16(pa[1][w2], vf, oacc[1][c5],0,0,0);
      }
    }

    if (t < 15){
      __syncthreads();
      *(int4*)((char*)Vlds + ((tid    )>>3)*144 + ((tid    )&7)*16) = vr0;
      *(int4*)((char*)Vlds + ((256+tid)>>3)*144 + ((256+tid)&7)*16) = vr1;
      if (tid < 64) *(int4*)((char*)Vlds + ((512+tid)>>3)*144 + ((512+tid)&7)*16) = vr2;
    }
  }

  size_t obase = (size_t)b*1024*1152 + (size_t)h*72;
  #pragma unroll
  for (int s=0;s<2;s++){
    float ls = lsum[s];
    ls += __shfl_xor(ls, 16);
    ls += __shfl_xor(ls, 32);
    float linv[4];
    #pragma unroll
    for (int r=0;r<4;r++) linv[r] = 1.0f / __shfl(ls, 4*g + r);
    #pragma unroll
    for (int c5=0;c5<5;c5++){
      int d = c5*16 + c;
      if (d < 72){
        #pragma unroll
        for (int r=0;r<4;r++){
          int n = q0 + wv*32 + s*16 + 4*g + r;
          O[obase + (size_t)n*1152 + d] = f2bf(oacc[s][c5][r]*linv[r]);
        }
      }
    }
  }
}

extern "C" void kernel_launch(void* const* d_in, const int* in_sizes, int n_in,
                              void* d_out, int out_size, void* d_ws, size_t ws_size,
                              hipStream_t stream) {
  const float* x    = (const float*)d_in[0];
  const float* temb = (const float*)d_in[1];
  const float* cos_y= (const float*)d_in[2];
  const float* sin_y= (const float*)d_in[3];
  const float* cos_x= (const float*)d_in[4];
  const float* sin_x= (const float*)d_in[5];
  const float* Wqkv = (const float*)d_in[6];
  const float* bqkv = (const float*)d_in[7];
  const float* Wt   = (const float*)d_in[8];
  const float* bt   = (const float*)d_in[9];
  const float* Wp   = (const float*)d_in[10];
  const float* bp   = (const float*)d_in[11];
  const float* qn_w = (const float*)d_in[12];
  const float* kn_w = (const float*)d_in[13];
  const float* Wg   = (const float*)d_in[14];
  const float* bg   = (const float*)d_in[15];
  const float* Wu   = (const float*)d_in[16];
  const float* bu   = (const float*)d_in[17];
  const float* Wd   = (const float*)d_in[18];
  const float* bd   = (const float*)d_in[19];

  char* ws = (char*)d_ws;
  size_t off = 0;
  auto alloc = [&](size_t bytes)->void*{
    off = (off + 255) & ~(size_t)255;
    void* p = ws + off; off += bytes; return p;
  };

  u16*   wbuf  = (u16*)alloc((size_t)6144*1152*2);          // shared bf16 weight buffer (max: gate+up interleaved)
  float* tvec  = (float*)alloc((size_t)16*3456*4);
  u16*   xn_bf = (u16*)alloc((size_t)16384*1152*2);         // norm1 out -> o (attn out) -> xn2
  u16*   qt    = (u16*)alloc((size_t)262144*72*2);          // gbuf starts here later
  u16*   kt    = (u16*)alloc((size_t)262144*72*2);
  u16*   vt    = (u16*)alloc((size_t)256*72*1024*2);
  if (off > ws_size) return;   // diagnostic guard: clean fail instead of OOB crash

  u16*   o_bf   = xn_bf;
  u16*   xn2_bf = xn_bf;
  u16*   gbuf   = qt;          // 100.7 MB <= qt+kt+vt region (113.2 MB)
  float* x1     = (float*)d_out;

  // norm1 + temb branch
  rms_kernel<<<16384,256,0,stream>>>(x, xn_bf, 1152);
  temb_kernel<<<(16*3456+255)/256,256,0,stream>>>(temb, Wt, bt, bqkv, tvec);

  // QKV GEMM (scatter epilogue -> qt/kt/vt); segw=9 -> B-seg 2.6 MB
  cvt_kernel<<<(3456*1152+255)/256,256,0,stream>>>(Wqkv, wbuf, 3456*1152);
  gemm_kernel<0><<<27*128,256,0,stream>>>(
      xn_bf, wbuf, 16384, 3456, 1152, 27, 9, nullptr, tvec, qt, kt, vt);

  // q/k RMS + RoPE in place (q pre-scaled by 1/sqrt(72))
  qkrope_kernel<<<65536,256,0,stream>>>(qt, kt, qn_w, kn_w, cos_y, sin_y, cos_x, sin_x);

  // attention -> o_bf
  attn_kernel<<<2048,256,0,stream>>>(qt, kt, vt, o_bf);

  // proj + residual -> x1 (= d_out, fp32); segw=9
  cvt_kernel<<<(1152*1152+255)/256,256,0,stream>>>(Wp, wbuf, 1152*1152);
  gemm_kernel<1><<<9*128,256,0,stream>>>(
      o_bf, wbuf, 16384, 1152, 1152, 9, 9, bp, x, x1, nullptr, nullptr);

  // norm2
  rms_kernel<<<16384,256,0,stream>>>(x1, xn2_bf, 1152);

  // gate+up fused (interleaved weights), silu in epilogue -> gbuf; segw=8 -> B-seg 2.4 MB
  cvt_gu_kernel<<<(6144*1152+255)/256,256,0,stream>>>(Wg, Wu, wbuf);
  gemm_kernel<5><<<48*128,256,0,stream>>>(
      xn2_bf, wbuf, 16384, 6144, 1152, 48, 8, bg, bu, gbuf, nullptr, nullptr);

  // down + residual -> d_out (reads x1 == d_out element-wise, race-free); segw=3 (K=3072 -> B-seg 2.4 MB)
  cvt_kernel<<<(1152*3072+255)/256,256,0,stream>>>(Wd, wbuf, 1152*3072);
  gemm_kernel<4><<<9*128,256,0,stream>>>(
      gbuf, wbuf, 16384, 1152, 3072, 9, 3, bd, x1, (float*)d_out, nullptr, nullptr);
}

// Round 7
// 1006.928 us; speedup vs baseline: 1.5701x; 1.0135x over previous
//
#include <hip/hip_runtime.h>
#include <cstdint>
#include <cstddef>

typedef unsigned short u16;
typedef unsigned int u32;
typedef __attribute__((ext_vector_type(8))) short bf16x8s;
typedef __attribute__((ext_vector_type(4))) float f32x4;

__device__ __forceinline__ u16 f2bf(float f){
  union { float f; unsigned u; } v; v.f = f;
  unsigned r = v.u + 0x7FFFu + ((v.u >> 16) & 1u);
  return (u16)(r >> 16);
}
__device__ __forceinline__ float bf2f(u16 h){
  union { unsigned u; float f; } v; v.u = ((unsigned)h) << 16;
  return v.f;
}

// ---------------- fp32 -> bf16 convert ----------------
__global__ __launch_bounds__(256) void cvt_kernel(const float* __restrict__ in,
                                                  u16* __restrict__ out, int n){
  int i = blockIdx.x*256 + threadIdx.x;
  if (i < n) out[i] = f2bf(in[i]);
}

// ---------------- Wg/Wu -> bf16 interleaved in 16-row blocks: out rows [6144][1152] ----------------
__global__ __launch_bounds__(256) void cvt_gu_kernel(const float* __restrict__ Wg,
                                                     const float* __restrict__ Wu,
                                                     u16* __restrict__ out){
  size_t i = (size_t)blockIdx.x*256 + threadIdx.x;   // over 6144*1152
  if (i >= (size_t)6144*1152) return;
  int j = (int)(i / 1152), k = (int)(i % 1152);
  int b16 = j >> 4, w = j & 15;
  int src = (b16 >> 1)*16 + w;
  const float* W = (b16 & 1) ? Wu : Wg;
  out[i] = f2bf(W[(size_t)src*1152 + k]);
}

// ---------------- temb branch: tvec[b][col] = temb@Wt^T + bt + bqkv ----------------
__global__ __launch_bounds__(256) void temb_kernel(const float* __restrict__ temb,
                                                   const float* __restrict__ Wt,
                                                   const float* __restrict__ bt,
                                                   const float* __restrict__ bqkv,
                                                   float* __restrict__ tvec){
  int idx = blockIdx.x*256 + threadIdx.x;
  if (idx >= 16*3456) return;
  int b = idx / 3456, col = idx % 3456;
  const float* tp = temb + (size_t)b*1152;
  const float* wp = Wt + (size_t)col*1152;
  float s = 0.f;
  for (int k=0;k<1152;k++) s += tp[k]*wp[k];
  tvec[idx] = s + bt[col] + bqkv[col];
}

// ---------------- row RMSNorm (no affine), fp32 in -> bf16 out ----------------
__global__ __launch_bounds__(256) void rms_kernel(const float* __restrict__ in,
                                                  u16* __restrict__ out, int C){
  int row = blockIdx.x;
  const float* p = in + (size_t)row*C;
  float ss = 0.f;
  for (int c = threadIdx.x; c < C; c += 256){ float v = p[c]; ss += v*v; }
  #pragma unroll
  for (int d=1; d<64; d<<=1) ss += __shfl_xor(ss, d);
  __shared__ float wsum[4];
  if ((threadIdx.x & 63) == 0) wsum[threadIdx.x>>6] = ss;
  __syncthreads();
  float tot = wsum[0]+wsum[1]+wsum[2]+wsum[3];
  float r = rsqrtf(tot/(float)C + 1e-6f);
  u16* o = out + (size_t)row*C;
  for (int c = threadIdx.x; c < C; c += 256) o[c] = f2bf(p[c]*r);
}

// ---------------- GEMM: Y[M][N] = A[M][K](bf16) @ B[N][K]^T(bf16) ----------------
// 3-deep LDS pipeline, counted vmcnt(4) in steady state (never drains mid-loop).
// Cache-aware block order (XCD chunk -> n-segment -> m-sweep).
// MODE 0: QKV scatter; 1: PROJ; 4: DOWN; 5: GATE+UP fused (N=6144 interleaved).
// Requires: NT = K/32 divisible by 3 (K=1152 -> 36, K=3072 -> 96); nwg%8==0,
// (nwg/8)%nbx==0, nbx%segw==0.
template<int MODE>
__global__ __launch_bounds__(256, 3) void gemm_kernel(
    const u16* __restrict__ A, const u16* __restrict__ B,
    int M, int N, int K, int nbx, int segw,
    const float* __restrict__ bias, const float* __restrict__ fextra,
    void* __restrict__ outv, u16* __restrict__ out2, u16* __restrict__ out3)
{
  __shared__ __align__(16) u16 As0[128*32];
  __shared__ __align__(16) u16 Bs0[128*32];
  __shared__ __align__(16) u16 As1[128*32];
  __shared__ __align__(16) u16 Bs1[128*32];
  __shared__ __align__(16) u16 As2[128*32];
  __shared__ __align__(16) u16 Bs2[128*32];
  const int tid  = threadIdx.x;
  const int lane = tid & 63;
  const int wv   = tid >> 6;
  const int wr   = wv >> 1, wc = wv & 1;

  // block-id remap: xcd chunk -> n-segment -> m-sweep -> n within segment
  const int nwg  = (int)gridDim.x;
  const int bid  = (int)blockIdx.x;
  const int xcd  = bid & 7;
  const int slot = bid >> 3;              // [0, nwg/8)
  const int mdep = (nwg >> 3) / nbx;      // m-rows per xcd chunk
  const int segsz = mdep * segw;
  const int seg  = slot / segsz;
  const int rem  = slot - seg*segsz;
  const int mi   = rem / segw;
  const int ni   = seg*segw + (rem - mi*segw);
  const long m0 = (long)(xcd*mdep + mi) * 128;
  const long n0 = (long)ni * 128;

  const u16* Ab = A + (size_t)m0*K;
  const u16* Bb = B + (size_t)n0*K;
  const int srow = tid >> 2;          // 0..63
  const int spos = (tid & 3) * 8;     // element offset of 16B chunk within 32-col row

  f32x4 acc[4][4];
  #pragma unroll
  for (int i=0;i<4;i++)
    #pragma unroll
    for (int j=0;j<4;j++) acc[i][j] = (f32x4){0.f,0.f,0.f,0.f};

  auto stage = [&](u16* as, u16* bs, int kt){
    __builtin_amdgcn_global_load_lds(
      (const __attribute__((address_space(1))) void*)(Ab + (size_t)srow*K + kt + spos),
      (__attribute__((address_space(3))) void*)(as + wv*512), 16, 0, 0);
    __builtin_amdgcn_global_load_lds(
      (const __attribute__((address_space(1))) void*)(Ab + (size_t)(64+srow)*K + kt + spos),
      (__attribute__((address_space(3))) void*)(as + 2048 + wv*512), 16, 0, 0);
    __builtin_amdgcn_global_load_lds(
      (const __attribute__((address_space(1))) void*)(Bb + (size_t)srow*K + kt + spos),
      (__attribute__((address_space(3))) void*)(bs + wv*512), 16, 0, 0);
    __builtin_amdgcn_global_load_lds(
      (const __attribute__((address_space(1))) void*)(Bb + (size_t)(64+srow)*K + kt + spos),
      (__attribute__((address_space(3))) void*)(bs + 2048 + wv*512), 16, 0, 0);
  };
  auto compute = [&](const u16* as, const u16* bs){
    const int kb = (lane>>4)*8;
    const int lc = lane & 15;
    bf16x8s af[4], bfr[4];
    #pragma unroll
    for (int i=0;i<4;i++)
      af[i] = *(const bf16x8s*)(as + (wr*64 + i*16 + lc)*32 + kb);
    #pragma unroll
    for (int j=0;j<4;j++)
      bfr[j] = *(const bf16x8s*)(bs + (wc*64 + j*16 + lc)*32 + kb);
    #pragma unroll
    for (int i=0;i<4;i++)
      #pragma unroll
      for (int j=0;j<4;j++)
        acc[i][j] = __builtin_amdgcn_mfma_f32_16x16x32_bf16(af[i], bfr[j], acc[i][j], 0,0,0);
  };

  const int NT = K >> 5;   // divisible by 3
  // prologue: tiles 0,1 in flight; wait for tile 0 only (tile 1's 4 loads stay in flight)
  stage(As0, Bs0, 0);
  stage(As1, Bs1, 32);
  asm volatile("s_waitcnt vmcnt(4)" ::: "memory");
  __builtin_amdgcn_s_barrier();
  __builtin_amdgcn_sched_barrier(0);

  for (int t = 0; t < NT; t += 3){
    // body A: compute tile t (buf0); stage tile t+2 -> buf2 (last read at body t-1, barrier-protected)
    if (t+2 < NT) stage(As2, Bs2, (t+2)*32);
    compute(As0, Bs0);
    if (t+2 < NT) asm volatile("s_waitcnt vmcnt(4)" ::: "memory");
    else          asm volatile("s_waitcnt vmcnt(0)" ::: "memory");
    __builtin_amdgcn_s_barrier();
    __builtin_amdgcn_sched_barrier(0);
    // body B: compute tile t+1 (buf1); stage tile t+3 -> buf0
    if (t+3 < NT) stage(As0, Bs0, (t+3)*32);
    compute(As1, Bs1);
    if (t+3 < NT) asm volatile("s_waitcnt vmcnt(4)" ::: "memory");
    else          asm volatile("s_waitcnt vmcnt(0)" ::: "memory");
    __builtin_amdgcn_s_barrier();
    __builtin_amdgcn_sched_barrier(0);
    // body C: compute tile t+2 (buf2); stage tile t+4 -> buf1
    if (t+4 < NT) stage(As1, Bs1, (t+4)*32);
    compute(As2, Bs2);
    if (t+4 < NT) asm volatile("s_waitcnt vmcnt(4)" ::: "memory");
    else          asm volatile("s_waitcnt vmcnt(0)" ::: "memory");
    __builtin_amdgcn_s_barrier();
    __builtin_amdgcn_sched_barrier(0);
  }

  const int lr = (lane>>4)*4, lc = lane&15;
  if (MODE==5){
    #pragma unroll
    for (int i=0;i<4;i++){
      #pragma unroll
      for (int jp=0;jp<2;jp++){
        long hcol = (n0>>1) + wc*32 + jp*16 + lc;
        float bgv = bias[hcol], buv = fextra[hcol];
        #pragma unroll
        for (int r=0;r<4;r++){
          long rowg = m0 + wr*64 + i*16 + lr + r;
          float gv = acc[i][2*jp][r] + bgv;
          float uv = acc[i][2*jp+1][r] + buv;
          float hv = (gv/(1.f + __expf(-gv))) * uv;
          ((u16*)outv)[(size_t)rowg*3072 + hcol] = f2bf(hv);
        }
      }
    }
    return;
  }
  #pragma unroll
  for (int i=0;i<4;i++){
    #pragma unroll
    for (int j=0;j<4;j++){
      long colg = n0 + wc*64 + j*16 + lc;
      long rowg0 = m0 + wr*64 + i*16 + lr;
      if (MODE==0){
        int cg = (int)colg;
        int which = cg / 1152;
        int rem2 = cg - which*1152;
        int hh = rem2 / 72, dd = rem2 - hh*72;
        int b = (int)(rowg0 >> 10), n = (int)(rowg0 & 1023);
        size_t bh = (size_t)(b*16 + hh);
        float tadd = fextra[(size_t)b*3456 + colg];
        if (which == 2){
          ushort4 vv;
          vv.x = f2bf(acc[i][j][0] + tadd);
          vv.y = f2bf(acc[i][j][1] + tadd);
          vv.z = f2bf(acc[i][j][2] + tadd);
          vv.w = f2bf(acc[i][j][3] + tadd);
          *(ushort4*)(out3 + (bh*72 + dd)*1024 + n) = vv;
        } else {
          u16* dst = (which==0) ? (u16*)outv : out2;
          #pragma unroll
          for (int r=0;r<4;r++)
            dst[(bh*1024 + (size_t)(n + r))*72 + dd] = f2bf(acc[i][j][r] + tadd);
        }
      } else {
        #pragma unroll
        for (int r=0;r<4;r++){
          long rowg = rowg0 + r;
          float v = acc[i][j][r];
          size_t oi = (size_t)rowg*N + colg;
          v += bias[colg] + fextra[oi];
          ((float*)outv)[oi] = v;
        }
      }
    }
  }
}

// ---------------- per-(b,h,n): q/k RMS(+weight) + axial RoPE, IN PLACE ----------------
__global__ __launch_bounds__(256) void qkrope_kernel(
    u16* __restrict__ Q, u16* __restrict__ K,
    const float* __restrict__ qn_w, const float* __restrict__ kn_w,
    const float* __restrict__ cos_y, const float* __restrict__ sin_y,
    const float* __restrict__ cos_x, const float* __restrict__ sin_x)
{
  const int gw   = blockIdx.x*4 + (threadIdx.x>>6);   // row over B*H*N = 262144
  const int lane = threadIdx.x & 63;
  const int n = gw & 1023;
  const int d0 = lane*2;
  const bool act = d0 < 72;
  const float scale = 0.11785113019775793f;  // 1/sqrt(72), folded into q

  u16* qp = Q + (size_t)gw*72;
  u16* kp = K + (size_t)gw*72;
  float q0=0,q1=0,k0=0,k1=0,wq0=0,wq1=0,wk0=0,wk1=0;
  if (act){
    q0 = bf2f(qp[d0]); q1 = bf2f(qp[d0+1]);
    k0 = bf2f(kp[d0]); k1 = bf2f(kp[d0+1]);
    wq0 = qn_w[d0]; wq1 = qn_w[d0+1];
    wk0 = kn_w[d0]; wk1 = kn_w[d0+1];
  }
  float ssq = q0*q0 + q1*q1;
  float ssk = k0*k0 + k1*k1;
  #pragma unroll
  for (int d=1; d<64; d<<=1){ ssq += __shfl_xor(ssq,d); ssk += __shfl_xor(ssk,d); }
  const float rq = rsqrtf(ssq*(1.f/72.f) + 1e-6f);
  const float rk = rsqrtf(ssk*(1.f/72.f) + 1e-6f);
  float qn0 = q0*rq*wq0, qn1 = q1*rq*wq1;
  float kn0 = k0*rk*wk0, kn1 = k1*rk*wk1;

  int dh = d0 % 36;
  const bool first = (dh < 18);
  int partner = first ? lane+9 : lane-9;
  if (!act) partner = lane;
  float pq0 = __shfl(qn0, partner), pq1 = __shfl(qn1, partner);
  float pk0 = __shfl(kn0, partner), pk1 = __shfl(kn1, partner);
  if (act){
    const float* cp = (d0 < 36) ? cos_y : cos_x;
    const float* sp = (d0 < 36) ? sin_y : sin_x;
    float c0 = cp[n*36+dh], c1 = cp[n*36+dh+1];
    float s0 = sp[n*36+dh], s1 = sp[n*36+dh+1];
    float sgn = first ? -1.f : 1.f;
    float qo0 = (qn0*c0 + sgn*pq0*s0)*scale, qo1 = (qn1*c1 + sgn*pq1*s1)*scale;
    float ko0 = kn0*c0 + sgn*pk0*s0,         ko1 = kn1*c1 + sgn*pk1*s1;
    *(unsigned*)(qp + d0) = (unsigned)f2bf(qo0) | ((unsigned)f2bf(qo1)<<16);
    *(unsigned*)(kp + d0) = (unsigned)f2bf(ko0) | ((unsigned)f2bf(ko1)<<16);
  }
}

// ---------------- flash attention: 4 waves x 32 q-rows (QBLK=128), KVB=64 ----------------
__global__ __launch_bounds__(256, 3) void attn_kernel(
    const u16* __restrict__ Q, const u16* __restrict__ K,
    const u16* __restrict__ Vt, u16* __restrict__ O)
{
  const int tid  = threadIdx.x;
  const int lane = tid & 63;
  const int wv   = tid >> 6;            // 0..3
  const int g = lane >> 4, c = lane & 15;
  const int bid  = blockIdx.x;
  const int head = (bid >> 6) * 8 + (bid & 7);   // XCD affinity: b%8 == head%8
  const int q0   = ((bid >> 3) & 7) * 128;
  const int b = head >> 4, h = head & 15;

  __shared__ __align__(16) u16 Vlds[80][72];      // [d][k] for current kv-tile; rows 72..79 zero
  __shared__ __align__(16) u16 Plds[8][16][64];   // [wv*2+s][q][k], XOR-swizzled rows

  const bf16x8s zf = {0,0,0,0,0,0,0,0};
  const u16* Kp = K + (size_t)head*1024*72;
  const u16* Qb = Q + ((size_t)head*1024 + q0 + wv*32)*72;
  const char* Vg = (const char*)(Vt + (size_t)head*72*1024);

  bf16x8s qf[2][3];
  #pragma unroll
  for (int s=0;s<2;s++){
    const u16* qrow = Qb + (size_t)(s*16 + c)*72;
    qf[s][0] = *(const bf16x8s*)(qrow + g*8);
    qf[s][1] = *(const bf16x8s*)(qrow + 32 + g*8);
    qf[s][2] = (g==0) ? *(const bf16x8s*)(qrow + 64) : zf;
  }

  f32x4 oacc[2][5];
  float lsum[2] = {0.f, 0.f};
  #pragma unroll
  for (int s=0;s<2;s++)
    #pragma unroll
    for (int c5=0;c5<5;c5++) oacc[s][c5] = (f32x4){0.f,0.f,0.f,0.f};

  char* pb0 = (char*)Plds + (wv*2+0)*2048 + c*128;
  char* pb1 = pb0 + 2048;
  const int swz = (c & 7) << 4;

  int4 vr0, vr1, vr2;
  {
    vr0 = *(const int4*)(Vg + ((tid    )>>3)*2048 + ((tid    )&7)*16);
    vr1 = *(const int4*)(Vg + ((256+tid)>>3)*2048 + ((256+tid)&7)*16);
    if (tid < 64) vr2 = *(const int4*)(Vg + ((512+tid)>>3)*2048 + ((512+tid)&7)*16);
  }
  if (tid < 288) ((u32*)&Vlds[72][0])[tid] = 0u;
  {
    *(int4*)((char*)Vlds + ((tid    )>>3)*144 + ((tid    )&7)*16) = vr0;
    *(int4*)((char*)Vlds + ((256+tid)>>3)*144 + ((256+tid)&7)*16) = vr1;
    if (tid < 64) *(int4*)((char*)Vlds + ((512+tid)>>3)*144 + ((512+tid)&7)*16) = vr2;
  }

  for (int t = 0; t < 16; ++t){
    const int kv0 = t*64;
    __syncthreads();
    if (t < 15){
      const char* vs = Vg + (kv0+64)*2;
      vr0 = *(const int4*)(vs + ((tid    )>>3)*2048 + ((tid    )&7)*16);
      vr1 = *(const int4*)(vs + ((256+tid)>>3)*2048 + ((256+tid)&7)*16);
      if (tid < 64) vr2 = *(const int4*)(vs + ((512+tid)>>3)*2048 + ((512+tid)&7)*16);
    }

    #pragma unroll
    for (int nf=0; nf<4; nf++){
      const u16* krow = Kp + (size_t)(kv0 + nf*16 + c)*72;
      bf16x8s kf0 = *(const bf16x8s*)(krow + g*8);
      bf16x8s kf1 = *(const bf16x8s*)(krow + 32 + g*8);
      bf16x8s kf2 = (g==0) ? *(const bf16x8s*)(krow + 64) : zf;
      #pragma unroll
      for (int s=0;s<2;s++){
        f32x4 sc = (f32x4){0.f,0.f,0.f,0.f};
        sc = __builtin_amdgcn_mfma_f32_16x16x32_bf16(kf0, qf[s][0], sc,0,0,0);
        sc = __builtin_amdgcn_mfma_f32_16x16x32_bf16(kf1, qf[s][1], sc,0,0,0);
        sc = __builtin_amdgcn_mfma_f32_16x16x32_bf16(kf2, qf[s][2], sc,0,0,0);
        float p0 = __expf(sc[0]), p1 = __expf(sc[1]);
        float p2 = __expf(sc[2]), p3 = __expf(sc[3]);
        lsum[s] += (p0+p1) + (p2+p3);
        u32 w0 = (u32)f2bf(p0) | ((u32)f2bf(p1) << 16);
        u32 w1 = (u32)f2bf(p2) | ((u32)f2bf(p3) << 16);
        char* pb = s ? pb1 : pb0;
        int kb = nf*32 + g*8;
        *(u32*)(pb + ( kb      ^ swz)) = w0;
        *(u32*)(pb + ((kb + 4) ^ swz)) = w1;
      }
    }
    asm volatile("" ::: "memory");
    bf16x8s pa[2][2];
    #pragma unroll
    for (int s=0;s<2;s++)
      #pragma unroll
      for (int w2=0;w2<2;w2++)
        pa[s][w2] = *(const bf16x8s*)((s?pb1:pb0) + ((w2*64 + g*16) ^ swz));

    #pragma unroll
    for (int c5=0;c5<5;c5++){
      #pragma unroll
      for (int w2=0;w2<2;w2++){
        bf16x8s vf = *(const bf16x8s*)((const char*)Vlds + (size_t)(c5*16+c)*144 + w2*64 + g*16);
        oacc[0][c5] = __builtin_amdgcn_mfma_f32_16x16x32_bf16(pa[0][w2], vf, oacc[0][c5],0,0,0);
        oacc[1][c5] = __builtin_amdgcn_mfma_f32_16x16x32_bf16(pa[1][w2], vf, oacc[1][c5],0,0,0);
      }
    }

    if (t < 15){
      __syncthreads();
      *(int4*)((char*)Vlds + ((tid    )>>3)*144 + ((tid    )&7)*16) = vr0;
      *(int4*)((char*)Vlds + ((256+tid)>>3)*144 + ((256+tid)&7)*16) = vr1;
      if (tid < 64) *(int4*)((char*)Vlds + ((512+tid)>>3)*144 + ((512+tid)&7)*16) = vr2;
    }
  }

  size_t obase = (size_t)b*1024*1152 + (size_t)h*72;
  #pragma unroll
  for (int s=0;s<2;s++){
    float ls = lsum[s];
    ls += __shfl_xor(ls, 16);
    ls += __shfl_xor(ls, 32);
    float linv[4];
    #pragma unroll
    for (int r=0;r<4;r++) linv[r] = 1.0f / __shfl(ls, 4*g + r);
    #pragma unroll
    for (int c5=0;c5<5;c5++){
      int d = c5*16 + c;
      if (d < 72){
        #pragma unroll
        for (int r=0;r<4;r++){
          int n = q0 + wv*32 + s*16 + 4*g + r;
          O[obase + (size_t)n*1152 + d] = f2bf(oacc[s][c5][r]*linv[r]);
        }
      }
    }
  }
}

extern "C" void kernel_launch(void* const* d_in, const int* in_sizes, int n_in,
                              void* d_out, int out_size, void* d_ws, size_t ws_size,
                              hipStream_t stream) {
  const float* x    = (const float*)d_in[0];
  const float* temb = (const float*)d_in[1];
  const float* cos_y= (const float*)d_in[2];
  const float* sin_y= (const float*)d_in[3];
  const float* cos_x= (const float*)d_in[4];
  const float* sin_x= (const float*)d_in[5];
  const float* Wqkv = (const float*)d_in[6];
  const float* bqkv = (const float*)d_in[7];
  const float* Wt   = (const float*)d_in[8];
  const float* bt   = (const float*)d_in[9];
  const float* Wp   = (const float*)d_in[10];
  const float* bp   = (const float*)d_in[11];
  const float* qn_w = (const float*)d_in[12];
  const float* kn_w = (const float*)d_in[13];
  const float* Wg   = (const float*)d_in[14];
  const float* bg   = (const float*)d_in[15];
  const float* Wu   = (const float*)d_in[16];
  const float* bu   = (const float*)d_in[17];
  const float* Wd   = (const float*)d_in[18];
  const float* bd   = (const float*)d_in[19];

  char* ws = (char*)d_ws;
  size_t off = 0;
  auto alloc = [&](size_t bytes)->void*{
    off = (off + 255) & ~(size_t)255;
    void* p = ws + off; off += bytes; return p;
  };

  u16*   wbuf  = (u16*)alloc((size_t)6144*1152*2);          // shared bf16 weight buffer (max: gate+up interleaved)
  float* tvec  = (float*)alloc((size_t)16*3456*4);
  u16*   xn_bf = (u16*)alloc((size_t)16384*1152*2);         // norm1 out -> o (attn out) -> xn2
  u16*   qt    = (u16*)alloc((size_t)262144*72*2);          // gbuf starts here later
  u16*   kt    = (u16*)alloc((size_t)262144*72*2);
  u16*   vt    = (u16*)alloc((size_t)256*72*1024*2);
  if (off > ws_size) return;   // diagnostic guard: clean fail instead of OOB crash

  u16*   o_bf   = xn_bf;
  u16*   xn2_bf = xn_bf;
  u16*   gbuf   = qt;          // 100.7 MB <= qt+kt+vt region (113.2 MB)
  float* x1     = (float*)d_out;

  // norm1 + temb branch
  rms_kernel<<<16384,256,0,stream>>>(x, xn_bf, 1152);
  temb_kernel<<<(16*3456+255)/256,256,0,stream>>>(temb, Wt, bt, bqkv, tvec);

  // QKV GEMM (scatter epilogue -> qt/kt/vt); segw=9 -> B-seg 2.6 MB
  cvt_kernel<<<(3456*1152+255)/256,256,0,stream>>>(Wqkv, wbuf, 3456*1152);
  gemm_kernel<0><<<27*128,256,0,stream>>>(
      xn_bf, wbuf, 16384, 3456, 1152, 27, 9, nullptr, tvec, qt, kt, vt);

  // q/k RMS + RoPE in place (q pre-scaled by 1/sqrt(72))
  qkrope_kernel<<<65536,256,0,stream>>>(qt, kt, qn_w, kn_w, cos_y, sin_y, cos_x, sin_x);

  // attention -> o_bf
  attn_kernel<<<2048,256,0,stream>>>(qt, kt, vt, o_bf);

  // proj + residual -> x1 (= d_out, fp32); segw=9
  cvt_kernel<<<(1152*1152+255)/256,256,0,stream>>>(Wp, wbuf, 1152*1152);
  gemm_kernel<1><<<9*128,256,0,stream>>>(
      o_bf, wbuf, 16384, 1152, 1152, 9, 9, bp, x, x1, nullptr, nullptr);

  // norm2
  rms_kernel<<<16384,256,0,stream>>>(x1, xn2_bf, 1152);

  // gate+up fused (interleaved weights), silu in epilogue -> gbuf; segw=8 -> B-seg 2.4 MB
  cvt_gu_kernel<<<(6144*1152+255)/256,256,0,stream>>>(Wg, Wu, wbuf);
  gemm_kernel<5><<<48*128,256,0,stream>>>(
      xn2_bf, wbuf, 16384, 6144, 1152, 48, 8, bg, bu, gbuf, nullptr, nullptr);

  // down + residual -> d_out (reads x1 == d_out element-wise, race-free); segw=3 (K=3072 -> B-seg 2.4 MB)
  cvt_kernel<<<(1152*3072+255)/256,256,0,stream>>>(Wd, wbuf, 1152*3072);
  gemm_kernel<4><<<9*128,256,0,stream>>>(
      gbuf, wbuf, 16384, 1152, 3072, 9, 3, bd, x1, (float*)d_out, nullptr, nullptr);
}